// Round 1
// baseline (539.447 us; speedup 1.0000x reference)
//
#include <hip/hip_runtime.h>
#include <math.h>

#define NEG_SLOPE 0.2f

// ---------------- CSR build ----------------
__global__ void k_deg(const int* __restrict__ ei, int E, int N, int* __restrict__ deg) {
    int i = blockIdx.x * blockDim.x + threadIdx.x;
    int Et = E + N;
    if (i >= Et) return;
    int dst = (i < E) ? ei[E + i] : (i - E);
    atomicAdd(&deg[dst], 1);
}

__global__ void k_scan_block(const int* __restrict__ deg, int N, int* __restrict__ excl, int* __restrict__ bsums) {
    __shared__ int s[256];
    int b = blockIdx.x, t = threadIdx.x;
    int i = b * 256 + t;
    int v = (i < N) ? deg[i] : 0;
    s[t] = v;
    __syncthreads();
    for (int off = 1; off < 256; off <<= 1) {
        int add = (t >= off) ? s[t - off] : 0;
        __syncthreads();
        s[t] += add;
        __syncthreads();
    }
    int incl = s[t];
    if (i < N) excl[i] = incl - v;
    if (t == 255) bsums[b] = incl;
}

__global__ void k_scan_sums(int* __restrict__ bsums, int NB) {
    __shared__ int s[256];
    int t = threadIdx.x;
    int v = (t < NB) ? bsums[t] : 0;
    s[t] = v;
    __syncthreads();
    for (int off = 1; off < 256; off <<= 1) {
        int add = (t >= off) ? s[t - off] : 0;
        __syncthreads();
        s[t] += add;
        __syncthreads();
    }
    if (t < NB) bsums[t] = s[t] - v;  // exclusive
}

__global__ void k_scan_add(int* __restrict__ row_start, const int* __restrict__ bsums, int N, int Et) {
    int i = blockIdx.x * blockDim.x + threadIdx.x;
    if (i < N) row_start[i] += bsums[blockIdx.x];
    if (i == 0) row_start[N] = Et;
}

__global__ void k_scatter(const int* __restrict__ ei, int E, int N, const int* __restrict__ row_start,
                          int* __restrict__ cursor, int* __restrict__ csr_src) {
    int i = blockIdx.x * blockDim.x + threadIdx.x;
    int Et = E + N;
    if (i >= Et) return;
    int src, dst;
    if (i < E) { src = ei[i]; dst = ei[E + i]; }
    else       { src = i - E; dst = i - E; }
    int pos = atomicAdd(&cursor[dst], 1);
    csr_src[row_start[dst] + pos] = src;
}

// ---------------- GEMM1: h1 = x @ W1  [N,256]x[256,256] fp32 ----------------
__global__ __launch_bounds__(256) void k_gemm1(const float* __restrict__ A, const float* __restrict__ B,
                                               float* __restrict__ C, int N) {
    __shared__ float As[16][64];
    __shared__ float Bs[16][64];
    int tid = threadIdx.x;
    int row0 = blockIdx.x * 64, col0 = blockIdx.y * 64;
    int tx = tid & 15, ty = tid >> 4;
    float acc[4][4] = {};
    for (int k0 = 0; k0 < 256; k0 += 16) {
#pragma unroll
        for (int i = 0; i < 4; i++) {
            int lin = tid + i * 256;
            int m = lin >> 4, k = lin & 15;
            int r = row0 + m;
            As[k][m] = (r < N) ? A[(size_t)r * 256 + k0 + k] : 0.f;
        }
#pragma unroll
        for (int i = 0; i < 4; i++) {
            int lin = tid + i * 256;
            int k = lin >> 6, n = lin & 63;
            Bs[k][n] = B[(size_t)(k0 + k) * 256 + col0 + n];
        }
        __syncthreads();
#pragma unroll
        for (int k = 0; k < 16; k++) {
            float a[4], bb[4];
#pragma unroll
            for (int i = 0; i < 4; i++) a[i] = As[k][ty * 4 + i];
#pragma unroll
            for (int j = 0; j < 4; j++) bb[j] = Bs[k][tx * 4 + j];
#pragma unroll
            for (int i = 0; i < 4; i++)
#pragma unroll
                for (int j = 0; j < 4; j++) acc[i][j] += a[i] * bb[j];
        }
        __syncthreads();
    }
#pragma unroll
    for (int i = 0; i < 4; i++) {
        int r = row0 + ty * 4 + i;
        if (r < N) {
#pragma unroll
            for (int j = 0; j < 4; j++) C[(size_t)r * 256 + col0 + tx * 4 + j] = acc[i][j];
        }
    }
}

// ---------------- attention dots layer1 ----------------
__global__ __launch_bounds__(256) void k_dots1(const float* __restrict__ h1, const float* __restrict__ att_s,
                                               const float* __restrict__ att_d, float* __restrict__ as1,
                                               float* __restrict__ ad1, int N) {
    int n = blockIdx.x;
    int t = threadIdx.x;
    int w = t >> 6, l = t & 63;
    float v = h1[(size_t)n * 256 + t];
    float ps = v * att_s[t];
    float pd = v * att_d[t];
    for (int off = 32; off; off >>= 1) {
        ps += __shfl_down(ps, off);
        pd += __shfl_down(pd, off);
    }
    if (l == 0) { as1[n * 4 + w] = ps; ad1[n * 4 + w] = pd; }
}

// ---------------- layer1 aggregation: wave per node ----------------
__global__ __launch_bounds__(256) void k_agg1(const float* __restrict__ h1, const float* __restrict__ as1,
                                              const float* __restrict__ ad1, const int* __restrict__ row_start,
                                              const int* __restrict__ csr_src, const float* __restrict__ b1,
                                              float* __restrict__ hout, int N) {
    int wv = threadIdx.x >> 6, l = threadIdx.x & 63;
    int n = blockIdx.x * 4 + wv;
    if (n >= N) return;
    int s0 = row_start[n], s1 = row_start[n + 1];
    float4 adv = *(const float4*)(ad1 + n * 4);
    // pass1: per-head max
    float m0 = -1e30f, m1 = -1e30f, m2 = -1e30f, m3 = -1e30f;
    for (int p = s0 + l; p < s1; p += 64) {
        int src = csr_src[p];
        float4 asv = *(const float4*)(as1 + src * 4);
        float e0 = asv.x + adv.x; e0 = e0 > 0.f ? e0 : NEG_SLOPE * e0;
        float e1 = asv.y + adv.y; e1 = e1 > 0.f ? e1 : NEG_SLOPE * e1;
        float e2 = asv.z + adv.z; e2 = e2 > 0.f ? e2 : NEG_SLOPE * e2;
        float e3 = asv.w + adv.w; e3 = e3 > 0.f ? e3 : NEG_SLOPE * e3;
        m0 = fmaxf(m0, e0); m1 = fmaxf(m1, e1); m2 = fmaxf(m2, e2); m3 = fmaxf(m3, e3);
    }
    for (int off = 32; off; off >>= 1) {
        m0 = fmaxf(m0, __shfl_xor(m0, off));
        m1 = fmaxf(m1, __shfl_xor(m1, off));
        m2 = fmaxf(m2, __shfl_xor(m2, off));
        m3 = fmaxf(m3, __shfl_xor(m3, off));
    }
    // pass2: exp-sum + unnormalized weighted aggregation
    float den0 = 0, den1 = 0, den2 = 0, den3 = 0;
    float acc0 = 0, acc1 = 0, acc2 = 0, acc3 = 0;
    for (int p = s0; p < s1; p++) {
        int src = csr_src[p];
        float4 asv = *(const float4*)(as1 + src * 4);
        float e0 = asv.x + adv.x; e0 = e0 > 0.f ? e0 : NEG_SLOPE * e0;
        float e1 = asv.y + adv.y; e1 = e1 > 0.f ? e1 : NEG_SLOPE * e1;
        float e2 = asv.z + adv.z; e2 = e2 > 0.f ? e2 : NEG_SLOPE * e2;
        float e3 = asv.w + adv.w; e3 = e3 > 0.f ? e3 : NEG_SLOPE * e3;
        float w0 = __expf(e0 - m0), w1 = __expf(e1 - m1), w2 = __expf(e2 - m2), w3 = __expf(e3 - m3);
        den0 += w0; den1 += w1; den2 += w2; den3 += w3;
        const float* hs = h1 + (size_t)src * 256;
        acc0 += w0 * hs[l];
        acc1 += w1 * hs[64 + l];
        acc2 += w2 * hs[128 + l];
        acc3 += w3 * hs[192 + l];
    }
    float o0 = acc0 / den0 + b1[l];
    float o1 = acc1 / den1 + b1[64 + l];
    float o2 = acc2 / den2 + b1[128 + l];
    float o3 = acc3 / den3 + b1[192 + l];
    float* ho = hout + (size_t)n * 256;
    ho[l]       = o0 > 0.f ? o0 : 0.f;
    ho[64 + l]  = o1 > 0.f ? o1 : 0.f;
    ho[128 + l] = o2 > 0.f ? o2 : 0.f;
    ho[192 + l] = o3 > 0.f ? o3 : 0.f;
}

// ---------------- GEMM2: h2 = h @ W2  [N,256]x[256,40] + att dots ----------------
__global__ __launch_bounds__(256) void k_gemm2(const float* __restrict__ h, const float* __restrict__ W2,
                                               const float* __restrict__ att_s2, const float* __restrict__ att_d2,
                                               float* __restrict__ h2, float* __restrict__ as2,
                                               float* __restrict__ ad2, int N) {
    __shared__ float Ws[256 * 40];
    int t = threadIdx.x;
    for (int i = t; i < 256 * 40; i += 256) Ws[i] = W2[i];
    __syncthreads();
    int r = t >> 2, g = t & 3;
    int row = blockIdx.x * 64 + r;
    if (row >= N) return;
    const float* hr = h + (size_t)row * 256;
    float acc[10] = {};
    for (int k = 0; k < 256; k++) {
        float x = hr[k];
        const float* w = &Ws[k * 40 + g * 10];
#pragma unroll
        for (int j = 0; j < 10; j++) acc[j] += x * w[j];
    }
    float ps = 0.f, pd = 0.f;
#pragma unroll
    for (int j = 0; j < 10; j++) {
        int c = g * 10 + j;
        h2[(size_t)row * 40 + c] = acc[j];
        ps += acc[j] * att_s2[c];
        pd += acc[j] * att_d2[c];
    }
    ps += __shfl_xor(ps, 1); ps += __shfl_xor(ps, 2);
    pd += __shfl_xor(pd, 1); pd += __shfl_xor(pd, 2);
    if (g == 0) { as2[row] = ps; ad2[row] = pd; }
}

// ---------------- layer2 aggregation + bias + log_softmax ----------------
__global__ __launch_bounds__(256) void k_agg2(const float* __restrict__ h2, const float* __restrict__ as2,
                                              const float* __restrict__ ad2, const int* __restrict__ row_start,
                                              const int* __restrict__ csr_src, const float* __restrict__ b2,
                                              float* __restrict__ out, int N) {
    int wv = threadIdx.x >> 6, l = threadIdx.x & 63;
    int n = blockIdx.x * 4 + wv;
    if (n >= N) return;
    int s0 = row_start[n], s1 = row_start[n + 1];
    float ad = ad2[n];
    float m = -1e30f;
    for (int p = s0 + l; p < s1; p += 64) {
        int src = csr_src[p];
        float e = as2[src] + ad; e = e > 0.f ? e : NEG_SLOPE * e;
        m = fmaxf(m, e);
    }
    for (int off = 32; off; off >>= 1) m = fmaxf(m, __shfl_xor(m, off));
    float den = 0.f, acc = 0.f;
    for (int p = s0; p < s1; p++) {
        int src = csr_src[p];
        float e = as2[src] + ad; e = e > 0.f ? e : NEG_SLOPE * e;
        float w = __expf(e - m);
        den += w;
        if (l < 40) acc += w * h2[(size_t)src * 40 + l];
    }
    float logit = (l < 40) ? (acc / den + b2[l]) : -1e30f;
    float mx = logit;
    for (int off = 32; off; off >>= 1) mx = fmaxf(mx, __shfl_xor(mx, off));
    float ex = (l < 40) ? __expf(logit - mx) : 0.f;
    float s = ex;
    for (int off = 32; off; off >>= 1) s += __shfl_xor(s, off);
    if (l < 40) out[(size_t)n * 40 + l] = logit - mx - logf(s);
}

extern "C" void kernel_launch(void* const* d_in, const int* in_sizes, int n_in,
                              void* d_out, int out_size, void* d_ws, size_t ws_size,
                              hipStream_t stream) {
    const float* x      = (const float*)d_in[0];
    const int*   ei     = (const int*)d_in[1];
    const float* W1     = (const float*)d_in[2];
    const float* att_s1 = (const float*)d_in[3];
    const float* att_d1 = (const float*)d_in[4];
    const float* b1     = (const float*)d_in[5];
    const float* W2     = (const float*)d_in[6];
    const float* att_s2 = (const float*)d_in[7];
    const float* att_d2 = (const float*)d_in[8];
    const float* b2     = (const float*)d_in[9];

    int N = in_sizes[0] / 256;
    int E = in_sizes[1] / 2;
    int Et = E + N;

    char* ws = (char*)d_ws;
    size_t off = 0;
    auto alloc = [&](size_t bytes) -> void* {
        void* p = ws + off;
        off += (bytes + 255) / 256 * 256;
        return p;
    };
    float* h1        = (float*)alloc((size_t)N * 256 * 4);
    float* hb        = (float*)alloc((size_t)N * 256 * 4);
    float* as1       = (float*)alloc((size_t)N * 4 * 4);
    float* ad1       = (float*)alloc((size_t)N * 4 * 4);
    float* h2        = (float*)alloc((size_t)N * 40 * 4);
    float* as2       = (float*)alloc((size_t)N * 4);
    float* ad2       = (float*)alloc((size_t)N * 4);
    int*   deg       = (int*)alloc((size_t)N * 4);
    int*   cursor    = (int*)alloc((size_t)N * 4);
    int*   row_start = (int*)alloc((size_t)(N + 1) * 4);
    int*   csr_src   = (int*)alloc((size_t)Et * 4);
    int NB = (N + 255) / 256;
    int*   bsums     = (int*)alloc((size_t)NB * 4);

    hipMemsetAsync(deg, 0, (size_t)N * 4, stream);
    hipMemsetAsync(cursor, 0, (size_t)N * 4, stream);

    k_deg<<<(Et + 255) / 256, 256, 0, stream>>>(ei, E, N, deg);
    k_scan_block<<<NB, 256, 0, stream>>>(deg, N, row_start, bsums);
    k_scan_sums<<<1, 256, 0, stream>>>(bsums, NB);
    k_scan_add<<<NB, 256, 0, stream>>>(row_start, bsums, N, Et);
    k_scatter<<<(Et + 255) / 256, 256, 0, stream>>>(ei, E, N, row_start, cursor, csr_src);

    dim3 g1((N + 63) / 64, 4);
    k_gemm1<<<g1, 256, 0, stream>>>(x, W1, h1, N);
    k_dots1<<<N, 256, 0, stream>>>(h1, att_s1, att_d1, as1, ad1, N);
    k_agg1<<<(N + 3) / 4, 256, 0, stream>>>(h1, as1, ad1, row_start, csr_src, b1, hb, N);
    k_gemm2<<<(N + 63) / 64, 256, 0, stream>>>(hb, W2, att_s2, att_d2, h2, as2, ad2, N);
    k_agg2<<<(N + 3) / 4, 256, 0, stream>>>(h2, as2, ad2, row_start, csr_src, b2, (float*)d_out, N);
}

// Round 2
// 447.067 us; speedup vs baseline: 1.2066x; 1.2066x over previous
//
#include <hip/hip_runtime.h>
#include <hip/hip_fp16.h>
#include <math.h>

#define NEG_SLOPE 0.2f

typedef short short8v __attribute__((ext_vector_type(8)));
typedef float f32x4 __attribute__((ext_vector_type(4)));

__device__ __forceinline__ unsigned short f2bf(float f) {
    unsigned int u = __builtin_bit_cast(unsigned int, f);
    u += 0x7FFFu + ((u >> 16) & 1u);   // RNE
    return (unsigned short)(u >> 16);
}

// ---------------- CSR build ----------------
__global__ void k_deg(const int* __restrict__ ei, int E, int N, int* __restrict__ deg) {
    int i = blockIdx.x * blockDim.x + threadIdx.x;
    int Et = E + N;
    if (i >= Et) return;
    int dst = (i < E) ? ei[E + i] : (i - E);
    atomicAdd(&deg[dst], 1);
}

__global__ void k_scan_block(const int* __restrict__ deg, int N, int* __restrict__ excl, int* __restrict__ bsums) {
    __shared__ int s[256];
    int b = blockIdx.x, t = threadIdx.x;
    int i = b * 256 + t;
    int v = (i < N) ? deg[i] : 0;
    s[t] = v;
    __syncthreads();
    for (int off = 1; off < 256; off <<= 1) {
        int add = (t >= off) ? s[t - off] : 0;
        __syncthreads();
        s[t] += add;
        __syncthreads();
    }
    int incl = s[t];
    if (i < N) excl[i] = incl - v;
    if (t == 255) bsums[b] = incl;
}

__global__ void k_scan_sums(int* __restrict__ bsums, int NB) {
    __shared__ int s[256];
    int t = threadIdx.x;
    int v = (t < NB) ? bsums[t] : 0;
    s[t] = v;
    __syncthreads();
    for (int off = 1; off < 256; off <<= 1) {
        int add = (t >= off) ? s[t - off] : 0;
        __syncthreads();
        s[t] += add;
        __syncthreads();
    }
    if (t < NB) bsums[t] = s[t] - v;  // exclusive
}

__global__ void k_scan_add(int* __restrict__ row_start, const int* __restrict__ bsums, int N, int Et) {
    int i = blockIdx.x * blockDim.x + threadIdx.x;
    if (i < N) row_start[i] += bsums[blockIdx.x];
    if (i == 0) row_start[N] = Et;
}

__global__ void k_scatter(const int* __restrict__ ei, int E, int N, const int* __restrict__ row_start,
                          int* __restrict__ cursor, int* __restrict__ csr_src) {
    int i = blockIdx.x * blockDim.x + threadIdx.x;
    int Et = E + N;
    if (i >= Et) return;
    int src, dst;
    if (i < E) { src = ei[i]; dst = ei[E + i]; }
    else       { src = i - E; dst = i - E; }
    int pos = atomicAdd(&cursor[dst], 1);
    csr_src[row_start[dst] + pos] = src;
}

// ---------------- dtype converts ----------------
__global__ void k_cvt_x(const float* __restrict__ x, unsigned short* __restrict__ xb, int total4) {
    int i = blockIdx.x * blockDim.x + threadIdx.x;
    if (i >= total4) return;
    float4 v = ((const float4*)x)[i];
    ushort4 o;
    o.x = f2bf(v.x); o.y = f2bf(v.y); o.z = f2bf(v.z); o.w = f2bf(v.w);
    ((ushort4*)xb)[i] = o;
}

// W1 [256 in][256 out] -> W1T bf16 [256 out][256 in]
__global__ void k_cvt_w1t(const float* __restrict__ W1, unsigned short* __restrict__ w1t) {
    int n = blockIdx.x, k = threadIdx.x;
    w1t[n * 256 + k] = f2bf(W1[k * 256 + n]);
}

// ---------------- GEMM1 via MFMA: h1 = x @ W1  [N,256]x[256,256] ----------------
#define LDP 264  // padded row stride in halfs (adds 16B pad -> bank skew)
__global__ __launch_bounds__(256) void k_gemm1_mfma(const unsigned short* __restrict__ xb,
                                                    const unsigned short* __restrict__ w1t,
                                                    float* __restrict__ C, int N) {
    __shared__ unsigned short As[64 * LDP];
    __shared__ unsigned short Bs[64 * LDP];
    int tid = threadIdx.x;
    int row0 = blockIdx.x * 64, col0 = blockIdx.y * 64;
    // stage A (x rows) and B (W1T rows = output cols), full K=256
#pragma unroll
    for (int it = 0; it < 8; it++) {
        int c = tid + it * 256;           // chunk id, 16B chunks; 64 rows * 32 chunks
        int r = c >> 5, q = c & 31;
        uint4 va = make_uint4(0, 0, 0, 0);
        if (row0 + r < N) va = ((const uint4*)xb)[(size_t)(row0 + r) * 32 + q];
        *(uint4*)&As[r * LDP + q * 8] = va;
        uint4 vb = ((const uint4*)w1t)[(size_t)(col0 + r) * 32 + q];
        *(uint4*)&Bs[r * LDP + q * 8] = vb;
    }
    __syncthreads();
    int w = tid >> 6, l = tid & 63;
    int hi = l >> 4, lo = l & 15;
    f32x4 acc[4] = {};
#pragma unroll
    for (int kk = 0; kk < 8; kk++) {
        short8v a = *(const short8v*)&As[(16 * w + lo) * LDP + kk * 32 + 8 * hi];
#pragma unroll
        for (int jb = 0; jb < 4; jb++) {
            short8v b = *(const short8v*)&Bs[(16 * jb + lo) * LDP + kk * 32 + 8 * hi];
            acc[jb] = __builtin_amdgcn_mfma_f32_16x16x32_bf16(a, b, acc[jb], 0, 0, 0);
        }
    }
    int col = col0 + lo;
#pragma unroll
    for (int jb = 0; jb < 4; jb++) {
#pragma unroll
        for (int j = 0; j < 4; j++) {
            int r = row0 + 16 * w + 4 * hi + j;
            if (r < N) C[(size_t)r * 256 + col + 16 * jb] = acc[jb][j];
        }
    }
}

// ---------------- attention dots layer1 + fp16 copy of h1 ----------------
__global__ __launch_bounds__(256) void k_dots1(const float* __restrict__ h1, const float* __restrict__ att_s,
                                               const float* __restrict__ att_d, float* __restrict__ as1,
                                               float* __restrict__ ad1, __half* __restrict__ h1h, int N) {
    int n = blockIdx.x;
    int t = threadIdx.x;
    int w = t >> 6, l = t & 63;
    float v = h1[(size_t)n * 256 + t];
    h1h[(size_t)n * 256 + t] = __float2half(v);
    float ps = v * att_s[t];
    float pd = v * att_d[t];
    for (int off = 32; off; off >>= 1) {
        ps += __shfl_down(ps, off);
        pd += __shfl_down(pd, off);
    }
    if (l == 0) { as1[n * 4 + w] = ps; ad1[n * 4 + w] = pd; }
}

// ---------------- layer1 edge softmax -> normalized alpha [Et][4] ----------------
__global__ __launch_bounds__(256) void k_alpha1(const float* __restrict__ as1, const float* __restrict__ ad1,
                                                const int* __restrict__ row_start, const int* __restrict__ csr_src,
                                                float* __restrict__ alpha, int N) {
    int wv = threadIdx.x >> 6, l = threadIdx.x & 63;
    int n = blockIdx.x * 4 + wv;
    if (n >= N) return;
    int s0 = row_start[n], s1 = row_start[n + 1];
    float4 adv = *(const float4*)(ad1 + n * 4);
    float m0 = -1e30f, m1 = -1e30f, m2 = -1e30f, m3 = -1e30f;
    for (int p = s0 + l; p < s1; p += 64) {
        int src = csr_src[p];
        float4 asv = *(const float4*)(as1 + src * 4);
        float e0 = asv.x + adv.x; e0 = e0 > 0.f ? e0 : NEG_SLOPE * e0;
        float e1 = asv.y + adv.y; e1 = e1 > 0.f ? e1 : NEG_SLOPE * e1;
        float e2 = asv.z + adv.z; e2 = e2 > 0.f ? e2 : NEG_SLOPE * e2;
        float e3 = asv.w + adv.w; e3 = e3 > 0.f ? e3 : NEG_SLOPE * e3;
        m0 = fmaxf(m0, e0); m1 = fmaxf(m1, e1); m2 = fmaxf(m2, e2); m3 = fmaxf(m3, e3);
    }
    for (int off = 32; off; off >>= 1) {
        m0 = fmaxf(m0, __shfl_xor(m0, off));
        m1 = fmaxf(m1, __shfl_xor(m1, off));
        m2 = fmaxf(m2, __shfl_xor(m2, off));
        m3 = fmaxf(m3, __shfl_xor(m3, off));
    }
    float d0 = 0, d1 = 0, d2 = 0, d3 = 0;
    for (int p = s0 + l; p < s1; p += 64) {
        int src = csr_src[p];
        float4 asv = *(const float4*)(as1 + src * 4);
        float e0 = asv.x + adv.x; e0 = e0 > 0.f ? e0 : NEG_SLOPE * e0;
        float e1 = asv.y + adv.y; e1 = e1 > 0.f ? e1 : NEG_SLOPE * e1;
        float e2 = asv.z + adv.z; e2 = e2 > 0.f ? e2 : NEG_SLOPE * e2;
        float e3 = asv.w + adv.w; e3 = e3 > 0.f ? e3 : NEG_SLOPE * e3;
        float4 wv4;
        wv4.x = __expf(e0 - m0); wv4.y = __expf(e1 - m1);
        wv4.z = __expf(e2 - m2); wv4.w = __expf(e3 - m3);
        ((float4*)alpha)[p] = wv4;
        d0 += wv4.x; d1 += wv4.y; d2 += wv4.z; d3 += wv4.w;
    }
    for (int off = 32; off; off >>= 1) {
        d0 += __shfl_xor(d0, off); d1 += __shfl_xor(d1, off);
        d2 += __shfl_xor(d2, off); d3 += __shfl_xor(d3, off);
    }
    float i0 = 1.f / d0, i1 = 1.f / d1, i2 = 1.f / d2, i3 = 1.f / d3;
    for (int p = s0 + l; p < s1; p += 64) {
        float4 wv4 = ((float4*)alpha)[p];
        wv4.x *= i0; wv4.y *= i1; wv4.z *= i2; wv4.w *= i3;
        ((float4*)alpha)[p] = wv4;
    }
}

// ---------------- layer1 aggregation: pure weighted gather (fp16) ----------------
__global__ __launch_bounds__(256) void k_agg1(const __half* __restrict__ h1h, const float* __restrict__ alpha,
                                              const int* __restrict__ row_start, const int* __restrict__ csr_src,
                                              const float* __restrict__ b1, float* __restrict__ hout, int N) {
    int wv = threadIdx.x >> 6, l = threadIdx.x & 63;
    int n = blockIdx.x * 4 + wv;
    if (n >= N) return;
    int s0 = row_start[n], s1 = row_start[n + 1];
    const __half2* h2p = (const __half2*)h1h;
    float axA = 0.f, ayA = 0.f, axB = 0.f, ayB = 0.f;
    for (int p = s0; p < s1; p++) {
        int src = csr_src[p];
        float4 a4 = ((const float4*)alpha)[p];
        float wA = (l < 32) ? a4.x : a4.y;   // heads 0/1
        float wB = (l < 32) ? a4.z : a4.w;   // heads 2/3
        float2 fA = __half22float2(h2p[src * 128 + l]);
        float2 fB = __half22float2(h2p[src * 128 + 64 + l]);
        axA += wA * fA.x; ayA += wA * fA.y;
        axB += wB * fB.x; ayB += wB * fB.y;
    }
    float2 bA = ((const float2*)b1)[l];
    float2 bB = ((const float2*)b1)[64 + l];
    float2 oA, oB;
    oA.x = axA + bA.x; oA.y = ayA + bA.y;
    oB.x = axB + bB.x; oB.y = ayB + bB.y;
    oA.x = oA.x > 0.f ? oA.x : 0.f; oA.y = oA.y > 0.f ? oA.y : 0.f;
    oB.x = oB.x > 0.f ? oB.x : 0.f; oB.y = oB.y > 0.f ? oB.y : 0.f;
    float2* op = (float2*)(hout + (size_t)n * 256);
    op[l] = oA;
    op[64 + l] = oB;
}

// ---------------- GEMM2 (k-tiled LDS) + att dots; h2 stored fp16 ----------------
__global__ __launch_bounds__(256) void k_gemm2(const float* __restrict__ hb, const float* __restrict__ W2,
                                               const float* __restrict__ att_s2, const float* __restrict__ att_d2,
                                               __half* __restrict__ h2h, float* __restrict__ as2,
                                               float* __restrict__ ad2, int N) {
    __shared__ float Ws[256 * 40];
    __shared__ float Hs[64][68];
    int t = threadIdx.x;
    for (int i = t; i < 256 * 40; i += 256) Ws[i] = W2[i];
    int row0 = blockIdx.x * 64;
    int r = t >> 2, g = t & 3;
    float acc[10] = {};
    for (int kt = 0; kt < 4; kt++) {
        __syncthreads();
#pragma unroll
        for (int it = 0; it < 4; it++) {
            int c = t + it * 256;          // 1024 float4 chunks: 64 rows x 16
            int rr = c >> 4, q = c & 15;
            float4 v = make_float4(0, 0, 0, 0);
            if (row0 + rr < N) v = ((const float4*)hb)[(size_t)(row0 + rr) * 64 + kt * 16 + q];
            *(float4*)&Hs[rr][q * 4] = v;
        }
        __syncthreads();
#pragma unroll 8
        for (int k = 0; k < 64; k++) {
            float x = Hs[r][k];
            const float* wp = &Ws[(kt * 64 + k) * 40 + g * 10];
#pragma unroll
            for (int j = 0; j < 10; j++) acc[j] += x * wp[j];
        }
    }
    int row = row0 + r;
    if (row >= N) return;
    float ps = 0.f, pd = 0.f;
#pragma unroll
    for (int j = 0; j < 10; j++) {
        int c = g * 10 + j;
        h2h[(size_t)row * 40 + c] = __float2half(acc[j]);
        ps += acc[j] * att_s2[c];
        pd += acc[j] * att_d2[c];
    }
    ps += __shfl_xor(ps, 1); ps += __shfl_xor(ps, 2);
    pd += __shfl_xor(pd, 1); pd += __shfl_xor(pd, 2);
    if (g == 0) { as2[row] = ps; ad2[row] = pd; }
}

// ---------------- layer2 edge softmax -> alpha2 [Et] ----------------
__global__ __launch_bounds__(256) void k_alpha2(const float* __restrict__ as2, const float* __restrict__ ad2,
                                                const int* __restrict__ row_start, const int* __restrict__ csr_src,
                                                float* __restrict__ alpha, int N) {
    int wv = threadIdx.x >> 6, l = threadIdx.x & 63;
    int n = blockIdx.x * 4 + wv;
    if (n >= N) return;
    int s0 = row_start[n], s1 = row_start[n + 1];
    float ad = ad2[n];
    float m = -1e30f;
    for (int p = s0 + l; p < s1; p += 64) {
        float e = as2[csr_src[p]] + ad; e = e > 0.f ? e : NEG_SLOPE * e;
        m = fmaxf(m, e);
    }
    for (int off = 32; off; off >>= 1) m = fmaxf(m, __shfl_xor(m, off));
    float den = 0.f;
    for (int p = s0 + l; p < s1; p += 64) {
        float e = as2[csr_src[p]] + ad; e = e > 0.f ? e : NEG_SLOPE * e;
        float w = __expf(e - m);
        alpha[p] = w;
        den += w;
    }
    for (int off = 32; off; off >>= 1) den += __shfl_xor(den, off);
    float inv = 1.f / den;
    for (int p = s0 + l; p < s1; p += 64) alpha[p] *= inv;
}

// ---------------- layer2 aggregation + bias + log_softmax ----------------
__global__ __launch_bounds__(256) void k_agg2(const __half* __restrict__ h2h, const float* __restrict__ alpha,
                                              const int* __restrict__ row_start, const int* __restrict__ csr_src,
                                              const float* __restrict__ b2, float* __restrict__ out, int N) {
    int wv = threadIdx.x >> 6, l = threadIdx.x & 63;
    int n = blockIdx.x * 4 + wv;
    if (n >= N) return;
    int s0 = row_start[n], s1 = row_start[n + 1];
    float acc = 0.f;
    for (int p = s0; p < s1; p++) {
        int src = csr_src[p];
        float w = alpha[p];
        if (l < 40) acc += w * __half2float(h2h[src * 40 + l]);
    }
    float logit = (l < 40) ? (acc + b2[l]) : -1e30f;
    float mx = logit;
    for (int off = 32; off; off >>= 1) mx = fmaxf(mx, __shfl_xor(mx, off));
    float ex = (l < 40) ? __expf(logit - mx) : 0.f;
    float s = ex;
    for (int off = 32; off; off >>= 1) s += __shfl_xor(s, off);
    if (l < 40) out[(size_t)n * 40 + l] = logit - mx - logf(s);
}

extern "C" void kernel_launch(void* const* d_in, const int* in_sizes, int n_in,
                              void* d_out, int out_size, void* d_ws, size_t ws_size,
                              hipStream_t stream) {
    const float* x      = (const float*)d_in[0];
    const int*   ei     = (const int*)d_in[1];
    const float* W1     = (const float*)d_in[2];
    const float* att_s1 = (const float*)d_in[3];
    const float* att_d1 = (const float*)d_in[4];
    const float* b1     = (const float*)d_in[5];
    const float* W2     = (const float*)d_in[6];
    const float* att_s2 = (const float*)d_in[7];
    const float* att_d2 = (const float*)d_in[8];
    const float* b2     = (const float*)d_in[9];

    int N = in_sizes[0] / 256;
    int E = in_sizes[1] / 2;
    int Et = E + N;

    char* ws = (char*)d_ws;
    size_t off = 0;
    auto alloc = [&](size_t bytes) -> void* {
        void* p = ws + off;
        off += (bytes + 255) / 256 * 256;
        return p;
    };
    // Region A: h1 fp32, later reused as hb (agg1 out) — agg1 reads only h1h
    float* h1  = (float*)alloc((size_t)N * 256 * 4);
    float* hb  = h1;
    // Region B: xb bf16 during gemm1, later alpha1 + alpha2 + h2h
    char* regB = (char*)alloc((size_t)N * 256 * 2);
    unsigned short* xb     = (unsigned short*)regB;
    float*          alpha1 = (float*)regB;                               // Et*16B
    float*          alpha2 = (float*)(regB + (size_t)Et * 16);           // Et*4B
    __half*         h2h    = (__half*)(regB + (size_t)Et * 20);          // N*40*2B
    // Region C: persistent fp16 h1 copy
    __half* h1h = (__half*)alloc((size_t)N * 256 * 2);

    unsigned short* w1t = (unsigned short*)alloc((size_t)256 * 256 * 2);
    float* as1 = (float*)alloc((size_t)N * 4 * 4);
    float* ad1 = (float*)alloc((size_t)N * 4 * 4);
    float* as2 = (float*)alloc((size_t)N * 4);
    float* ad2 = (float*)alloc((size_t)N * 4);
    int* deg       = (int*)alloc((size_t)N * 4);
    int* cursor    = (int*)alloc((size_t)N * 4);
    int* row_start = (int*)alloc((size_t)(N + 1) * 4);
    int* csr_src   = (int*)alloc((size_t)Et * 4);
    int NB = (N + 255) / 256;
    int* bsums = (int*)alloc((size_t)NB * 4);

    hipMemsetAsync(deg, 0, (size_t)N * 4, stream);
    hipMemsetAsync(cursor, 0, (size_t)N * 4, stream);

    k_deg<<<(Et + 255) / 256, 256, 0, stream>>>(ei, E, N, deg);
    k_scan_block<<<NB, 256, 0, stream>>>(deg, N, row_start, bsums);
    k_scan_sums<<<1, 256, 0, stream>>>(bsums, NB);
    k_scan_add<<<NB, 256, 0, stream>>>(row_start, bsums, N, Et);
    k_scatter<<<(Et + 255) / 256, 256, 0, stream>>>(ei, E, N, row_start, cursor, csr_src);

    k_cvt_x<<<(N * 64 + 255) / 256, 256, 0, stream>>>(x, xb, N * 64);
    k_cvt_w1t<<<256, 256, 0, stream>>>(W1, w1t);

    dim3 g1((N + 63) / 64, 4);
    k_gemm1_mfma<<<g1, 256, 0, stream>>>(xb, w1t, h1, N);
    k_dots1<<<N, 256, 0, stream>>>(h1, att_s1, att_d1, as1, ad1, h1h, N);
    k_alpha1<<<(N + 3) / 4, 256, 0, stream>>>(as1, ad1, row_start, csr_src, alpha1, N);
    k_agg1<<<(N + 3) / 4, 256, 0, stream>>>(h1h, alpha1, row_start, csr_src, b1, hb, N);
    k_gemm2<<<(N + 63) / 64, 256, 0, stream>>>(hb, W2, att_s2, att_d2, h2h, as2, ad2, N);
    k_alpha2<<<(N + 3) / 4, 256, 0, stream>>>(as2, ad2, row_start, csr_src, alpha2, N);
    k_agg2<<<(N + 3) / 4, 256, 0, stream>>>(h2h, alpha2, row_start, csr_src, b2, (float*)d_out, N);
}

// Round 3
// 337.158 us; speedup vs baseline: 1.6000x; 1.3260x over previous
//
#include <hip/hip_runtime.h>
#include <hip/hip_fp16.h>
#include <math.h>

#define NEG_SLOPE 0.2f

typedef short short8v __attribute__((ext_vector_type(8)));
typedef _Float16 half8v __attribute__((ext_vector_type(8)));
typedef float f32x4 __attribute__((ext_vector_type(4)));

__device__ __forceinline__ unsigned short f2bf(float f) {
    unsigned int u = __builtin_bit_cast(unsigned int, f);
    u += 0x7FFFu + ((u >> 16) & 1u);   // RNE
    return (unsigned short)(u >> 16);
}

__device__ __forceinline__ void fma_h4(float4& acc, float w, uint2 v) {
    __half2 p0 = __builtin_bit_cast(__half2, v.x);
    __half2 p1 = __builtin_bit_cast(__half2, v.y);
    float2 f0 = __half22float2(p0), f1 = __half22float2(p1);
    acc.x += w * f0.x; acc.y += w * f0.y; acc.z += w * f1.x; acc.w += w * f1.y;
}

// ---------------- CSR build ----------------
__global__ void k_deg(const int* __restrict__ ei, int E, int N, int* __restrict__ deg) {
    int i = blockIdx.x * blockDim.x + threadIdx.x;
    int Et = E + N;
    if (i >= Et) return;
    int dst = (i < E) ? ei[E + i] : (i - E);
    atomicAdd(&deg[dst], 1);
}

__global__ void k_scan_block(const int* __restrict__ deg, int N, int* __restrict__ excl, int* __restrict__ bsums) {
    __shared__ int s[256];
    int b = blockIdx.x, t = threadIdx.x;
    int i = b * 256 + t;
    int v = (i < N) ? deg[i] : 0;
    s[t] = v;
    __syncthreads();
    for (int off = 1; off < 256; off <<= 1) {
        int add = (t >= off) ? s[t - off] : 0;
        __syncthreads();
        s[t] += add;
        __syncthreads();
    }
    int incl = s[t];
    if (i < N) excl[i] = incl - v;
    if (t == 255) bsums[b] = incl;
}

__global__ void k_scan_sums(int* __restrict__ bsums, int NB) {
    __shared__ int s[256];
    int t = threadIdx.x;
    int v = (t < NB) ? bsums[t] : 0;
    s[t] = v;
    __syncthreads();
    for (int off = 1; off < 256; off <<= 1) {
        int add = (t >= off) ? s[t - off] : 0;
        __syncthreads();
        s[t] += add;
        __syncthreads();
    }
    if (t < NB) bsums[t] = s[t] - v;  // exclusive
}

__global__ void k_scan_add(int* __restrict__ row_start, const int* __restrict__ bsums, int N, int Et) {
    int i = blockIdx.x * blockDim.x + threadIdx.x;
    if (i < N) row_start[i] += bsums[blockIdx.x];
    if (i == 0) row_start[N] = Et;
}

__global__ void k_scatter(const int* __restrict__ ei, int E, int N, const int* __restrict__ row_start,
                          int* __restrict__ cursor, int* __restrict__ csr_src, int* __restrict__ csr_dst) {
    int i = blockIdx.x * blockDim.x + threadIdx.x;
    int Et = E + N;
    if (i >= Et) return;
    int src, dst;
    if (i < E) { src = ei[i]; dst = ei[E + i]; }
    else       { src = i - E; dst = i - E; }
    int pos = atomicAdd(&cursor[dst], 1);
    int slot = row_start[dst] + pos;
    csr_src[slot] = src;
    csr_dst[slot] = dst;
}

// ---------------- dtype converts ----------------
__global__ void k_cvt_x(const float* __restrict__ x, unsigned short* __restrict__ xb, int total4) {
    int i = blockIdx.x * blockDim.x + threadIdx.x;
    if (i >= total4) return;
    float4 v = ((const float4*)x)[i];
    ushort4 o;
    o.x = f2bf(v.x); o.y = f2bf(v.y); o.z = f2bf(v.z); o.w = f2bf(v.w);
    ((ushort4*)xb)[i] = o;
}

// W1 [256 in][256 out] -> W1T bf16 [256 out][256 in]
__global__ void k_cvt_w1t(const float* __restrict__ W1, unsigned short* __restrict__ w1t) {
    int n = blockIdx.x, k = threadIdx.x;
    w1t[n * 256 + k] = f2bf(W1[k * 256 + n]);
}

// W2 [256][40] -> W2T fp16 [48 pad][256]
__global__ void k_cvt_w2t(const float* __restrict__ W2, __half* __restrict__ w2t) {
    int c = blockIdx.x, k = threadIdx.x;
    w2t[c * 256 + k] = __float2half((c < 40) ? W2[k * 40 + c] : 0.f);
}

// ---------------- GEMM1 MFMA + fused att dots; writes h1h fp16 ----------------
#define LDP 264
__global__ __launch_bounds__(256) void k_gemm1_mfma(const unsigned short* __restrict__ xb,
                                                    const unsigned short* __restrict__ w1t,
                                                    const float* __restrict__ att_s,
                                                    const float* __restrict__ att_d,
                                                    __half* __restrict__ h1h,
                                                    float* __restrict__ as1, float* __restrict__ ad1, int N) {
    __shared__ unsigned short As[64 * LDP];
    __shared__ unsigned short Bs[64 * LDP];
    int tid = threadIdx.x;
    int row0 = blockIdx.x * 64;
    int head = blockIdx.y;
    int col0 = head * 64;
#pragma unroll
    for (int it = 0; it < 8; it++) {
        int c = tid + it * 256;
        int r = c >> 5, q = c & 31;
        uint4 va = make_uint4(0, 0, 0, 0);
        if (row0 + r < N) va = ((const uint4*)xb)[(size_t)(row0 + r) * 32 + q];
        *(uint4*)&As[r * LDP + q * 8] = va;
        uint4 vb = ((const uint4*)w1t)[(size_t)(col0 + r) * 32 + q];
        *(uint4*)&Bs[r * LDP + q * 8] = vb;
    }
    __syncthreads();
    int w = tid >> 6, l = tid & 63;
    int hi = l >> 4, lo = l & 15;
    f32x4 acc[4] = {};
#pragma unroll
    for (int kk = 0; kk < 8; kk++) {
        short8v a = *(const short8v*)&As[(16 * w + lo) * LDP + kk * 32 + 8 * hi];
#pragma unroll
        for (int jb = 0; jb < 4; jb++) {
            short8v b = *(const short8v*)&Bs[(16 * jb + lo) * LDP + kk * 32 + 8 * hi];
            acc[jb] = __builtin_amdgcn_mfma_f32_16x16x32_bf16(a, b, acc[jb], 0, 0, 0);
        }
    }
    float asr[4], adr[4];
#pragma unroll
    for (int jb = 0; jb < 4; jb++) {
        int c = col0 + lo + 16 * jb;
        asr[jb] = att_s[c];
        adr[jb] = att_d[c];
    }
#pragma unroll
    for (int j = 0; j < 4; j++) {
        int r = row0 + 16 * w + 4 * hi + j;
        float s = 0.f, d = 0.f;
#pragma unroll
        for (int jb = 0; jb < 4; jb++) {
            float v = acc[jb][j];
            s += v * asr[jb];
            d += v * adr[jb];
            if (r < N) h1h[(size_t)r * 256 + col0 + lo + 16 * jb] = __float2half(v);
        }
        s += __shfl_xor(s, 1); s += __shfl_xor(s, 2); s += __shfl_xor(s, 4); s += __shfl_xor(s, 8);
        d += __shfl_xor(d, 1); d += __shfl_xor(d, 2); d += __shfl_xor(d, 4); d += __shfl_xor(d, 8);
        if (lo == 0 && r < N) { as1[r * 4 + head] = s; ad1[r * 4 + head] = d; }
    }
}

// ---------------- edge-parallel e (layer1, 4 heads) ----------------
__global__ void k_edge_e1(const float* __restrict__ as1, const float* __restrict__ ad1,
                          const int* __restrict__ csr_src, const int* __restrict__ csr_dst,
                          float* __restrict__ e1, int Et) {
    int p = blockIdx.x * blockDim.x + threadIdx.x;
    if (p >= Et) return;
    int src = csr_src[p], dst = csr_dst[p];
    float4 a = ((const float4*)as1)[src];
    float4 d = ((const float4*)ad1)[dst];
    float4 e;
    e.x = a.x + d.x; e.x = e.x > 0.f ? e.x : NEG_SLOPE * e.x;
    e.y = a.y + d.y; e.y = e.y > 0.f ? e.y : NEG_SLOPE * e.y;
    e.z = a.z + d.z; e.z = e.z > 0.f ? e.z : NEG_SLOPE * e.z;
    e.w = a.w + d.w; e.w = e.w > 0.f ? e.w : NEG_SLOPE * e.w;
    ((float4*)e1)[p] = e;
}

// ---------------- per-node softmax normalize (layer1): e -> exp(e-m), inv_den ----------------
__global__ __launch_bounds__(256) void k_norm1(float* __restrict__ alpha, const int* __restrict__ row_start,
                                               float* __restrict__ inv_den, int N) {
    int wv = threadIdx.x >> 6, l = threadIdx.x & 63;
    int n = blockIdx.x * 4 + wv;
    if (n >= N) return;
    int s0 = row_start[n], s1 = row_start[n + 1];
    float m0 = -1e30f, m1 = -1e30f, m2 = -1e30f, m3 = -1e30f;
    for (int p = s0 + l; p < s1; p += 64) {
        float4 e = ((const float4*)alpha)[p];
        m0 = fmaxf(m0, e.x); m1 = fmaxf(m1, e.y); m2 = fmaxf(m2, e.z); m3 = fmaxf(m3, e.w);
    }
    for (int off = 32; off; off >>= 1) {
        m0 = fmaxf(m0, __shfl_xor(m0, off)); m1 = fmaxf(m1, __shfl_xor(m1, off));
        m2 = fmaxf(m2, __shfl_xor(m2, off)); m3 = fmaxf(m3, __shfl_xor(m3, off));
    }
    float d0 = 0.f, d1 = 0.f, d2 = 0.f, d3 = 0.f;
    for (int p = s0 + l; p < s1; p += 64) {
        float4 e = ((const float4*)alpha)[p];
        e.x = __expf(e.x - m0); e.y = __expf(e.y - m1);
        e.z = __expf(e.z - m2); e.w = __expf(e.w - m3);
        ((float4*)alpha)[p] = e;
        d0 += e.x; d1 += e.y; d2 += e.z; d3 += e.w;
    }
    for (int off = 32; off; off >>= 1) {
        d0 += __shfl_xor(d0, off); d1 += __shfl_xor(d1, off);
        d2 += __shfl_xor(d2, off); d3 += __shfl_xor(d3, off);
    }
    if (l == 0) {
        float4 iv; iv.x = 1.f / d0; iv.y = 1.f / d1; iv.z = 1.f / d2; iv.w = 1.f / d3;
        ((float4*)inv_den)[n] = iv;
    }
}

// ---------------- layer1 aggregation: 8B/lane gathers, unroll 4 ----------------
__global__ __launch_bounds__(256) void k_agg1(const __half* __restrict__ h1h, const float* __restrict__ alpha,
                                              const float* __restrict__ inv_den, const int* __restrict__ row_start,
                                              const int* __restrict__ csr_src, const float* __restrict__ b1,
                                              __half* __restrict__ hbh, int N) {
    int wv = threadIdx.x >> 6, l = threadIdx.x & 63;
    int n = blockIdx.x * 4 + wv;
    if (n >= N) return;
    int s0 = row_start[n], s1 = row_start[n + 1];
    int head = l >> 4;
    float4 acc = make_float4(0, 0, 0, 0);
    int p = s0;
    for (; p + 4 <= s1; p += 4) {
        int sA = csr_src[p], sB = csr_src[p + 1], sC = csr_src[p + 2], sD = csr_src[p + 3];
        float wA = alpha[(size_t)p * 4 + head];
        float wB = alpha[(size_t)(p + 1) * 4 + head];
        float wC = alpha[(size_t)(p + 2) * 4 + head];
        float wD = alpha[(size_t)(p + 3) * 4 + head];
        uint2 vA = *(const uint2*)&h1h[(size_t)sA * 256 + 4 * l];
        uint2 vB = *(const uint2*)&h1h[(size_t)sB * 256 + 4 * l];
        uint2 vC = *(const uint2*)&h1h[(size_t)sC * 256 + 4 * l];
        uint2 vD = *(const uint2*)&h1h[(size_t)sD * 256 + 4 * l];
        fma_h4(acc, wA, vA); fma_h4(acc, wB, vB); fma_h4(acc, wC, vC); fma_h4(acc, wD, vD);
    }
    for (; p < s1; p++) {
        int s = csr_src[p];
        float w = alpha[(size_t)p * 4 + head];
        uint2 v = *(const uint2*)&h1h[(size_t)s * 256 + 4 * l];
        fma_h4(acc, w, v);
    }
    float inv = inv_den[n * 4 + head];
    float4 b = ((const float4*)b1)[l];
    float r0 = acc.x * inv + b.x; r0 = r0 > 0.f ? r0 : 0.f;
    float r1 = acc.y * inv + b.y; r1 = r1 > 0.f ? r1 : 0.f;
    float r2 = acc.z * inv + b.z; r2 = r2 > 0.f ? r2 : 0.f;
    float r3 = acc.w * inv + b.w; r3 = r3 > 0.f ? r3 : 0.f;
    unsigned short u0 = __builtin_bit_cast(unsigned short, __float2half(r0));
    unsigned short u1 = __builtin_bit_cast(unsigned short, __float2half(r1));
    unsigned short u2 = __builtin_bit_cast(unsigned short, __float2half(r2));
    unsigned short u3 = __builtin_bit_cast(unsigned short, __float2half(r3));
    uint2 st;
    st.x = (unsigned)u0 | ((unsigned)u1 << 16);
    st.y = (unsigned)u2 | ((unsigned)u3 << 16);
    *(uint2*)&hbh[(size_t)n * 256 + 4 * l] = st;
}

// ---------------- GEMM2 via f16 MFMA + fused att dots ----------------
__global__ __launch_bounds__(256) void k_gemm2_mfma(const _Float16* __restrict__ hbh,
                                                    const _Float16* __restrict__ w2t,
                                                    const float* __restrict__ att_s2,
                                                    const float* __restrict__ att_d2,
                                                    __half* __restrict__ h2h,
                                                    float* __restrict__ as2, float* __restrict__ ad2, int N) {
    int tid = threadIdx.x, w = tid >> 6, l = tid & 63;
    int hi = l >> 4, lo = l & 15;
    int row0 = blockIdx.x * 64;
    int arow = row0 + 16 * w + lo;
    f32x4 acc[3] = {};
#pragma unroll
    for (int kk = 0; kk < 8; kk++) {
        half8v a = {};
        if (arow < N) a = *(const half8v*)&hbh[(size_t)arow * 256 + kk * 32 + 8 * hi];
#pragma unroll
        for (int jb = 0; jb < 3; jb++) {
            half8v b = *(const half8v*)&w2t[(16 * jb + lo) * 256 + kk * 32 + 8 * hi];
            acc[jb] = __builtin_amdgcn_mfma_f32_16x16x32_f16(a, b, acc[jb], 0, 0, 0);
        }
    }
    float asr[3], adr[3];
#pragma unroll
    for (int jb = 0; jb < 3; jb++) {
        int c = 16 * jb + lo;
        asr[jb] = (c < 40) ? att_s2[c] : 0.f;
        adr[jb] = (c < 40) ? att_d2[c] : 0.f;
    }
#pragma unroll
    for (int j = 0; j < 4; j++) {
        int r = row0 + 16 * w + 4 * hi + j;
        float s = 0.f, d = 0.f;
#pragma unroll
        for (int jb = 0; jb < 3; jb++) {
            float v = acc[jb][j];
            s += v * asr[jb];
            d += v * adr[jb];
            int c = 16 * jb + lo;
            if (c < 40 && r < N) h2h[(size_t)r * 40 + c] = __float2half(v);
        }
        s += __shfl_xor(s, 1); s += __shfl_xor(s, 2); s += __shfl_xor(s, 4); s += __shfl_xor(s, 8);
        d += __shfl_xor(d, 1); d += __shfl_xor(d, 2); d += __shfl_xor(d, 4); d += __shfl_xor(d, 8);
        if (lo == 0 && r < N) { as2[r] = s; ad2[r] = d; }
    }
}

// ---------------- edge-parallel e (layer2) ----------------
__global__ void k_edge_e2(const float* __restrict__ as2, const float* __restrict__ ad2,
                          const int* __restrict__ csr_src, const int* __restrict__ csr_dst,
                          float* __restrict__ e2, int Et) {
    int p = blockIdx.x * blockDim.x + threadIdx.x;
    if (p >= Et) return;
    float e = as2[csr_src[p]] + ad2[csr_dst[p]];
    e2[p] = e > 0.f ? e : NEG_SLOPE * e;
}

__global__ __launch_bounds__(256) void k_norm2(float* __restrict__ alpha, const int* __restrict__ row_start,
                                               float* __restrict__ inv_den, int N) {
    int wv = threadIdx.x >> 6, l = threadIdx.x & 63;
    int n = blockIdx.x * 4 + wv;
    if (n >= N) return;
    int s0 = row_start[n], s1 = row_start[n + 1];
    float m = -1e30f;
    for (int p = s0 + l; p < s1; p += 64) m = fmaxf(m, alpha[p]);
    for (int off = 32; off; off >>= 1) m = fmaxf(m, __shfl_xor(m, off));
    float den = 0.f;
    for (int p = s0 + l; p < s1; p += 64) {
        float w = __expf(alpha[p] - m);
        alpha[p] = w;
        den += w;
    }
    for (int off = 32; off; off >>= 1) den += __shfl_xor(den, off);
    if (l == 0) inv_den[n] = 1.f / den;
}

// ---------------- layer2 aggregation + bias + log_softmax ----------------
__global__ __launch_bounds__(256) void k_agg2(const __half* __restrict__ h2h, const float* __restrict__ alpha,
                                              const float* __restrict__ inv_den, const int* __restrict__ row_start,
                                              const int* __restrict__ csr_src, const float* __restrict__ b2,
                                              float* __restrict__ out, int N) {
    int wv = threadIdx.x >> 6, l = threadIdx.x & 63;
    int n = blockIdx.x * 4 + wv;
    if (n >= N) return;
    int s0 = row_start[n], s1 = row_start[n + 1];
    float2 acc = make_float2(0.f, 0.f);
    int p = s0;
    for (; p + 4 <= s1; p += 4) {
        int sA = csr_src[p], sB = csr_src[p + 1], sC = csr_src[p + 2], sD = csr_src[p + 3];
        float wA = alpha[p], wB = alpha[p + 1], wC = alpha[p + 2], wD = alpha[p + 3];
        if (l < 20) {
            unsigned vA = *(const unsigned*)&h2h[(size_t)sA * 40 + 2 * l];
            unsigned vB = *(const unsigned*)&h2h[(size_t)sB * 40 + 2 * l];
            unsigned vC = *(const unsigned*)&h2h[(size_t)sC * 40 + 2 * l];
            unsigned vD = *(const unsigned*)&h2h[(size_t)sD * 40 + 2 * l];
            float2 fA = __half22float2(__builtin_bit_cast(__half2, vA));
            float2 fB = __half22float2(__builtin_bit_cast(__half2, vB));
            float2 fC = __half22float2(__builtin_bit_cast(__half2, vC));
            float2 fD = __half22float2(__builtin_bit_cast(__half2, vD));
            acc.x += wA * fA.x + wB * fB.x + wC * fC.x + wD * fD.x;
            acc.y += wA * fA.y + wB * fB.y + wC * fC.y + wD * fD.y;
        }
    }
    for (; p < s1; p++) {
        int s = csr_src[p];
        float w = alpha[p];
        if (l < 20) {
            unsigned v = *(const unsigned*)&h2h[(size_t)s * 40 + 2 * l];
            float2 f = __half22float2(__builtin_bit_cast(__half2, v));
            acc.x += w * f.x;
            acc.y += w * f.y;
        }
    }
    float inv = inv_den[n];
    float lg0 = -1e30f, lg1 = -1e30f;
    if (l < 20) {
        lg0 = acc.x * inv + b2[2 * l];
        lg1 = acc.y * inv + b2[2 * l + 1];
    }
    float mx = fmaxf(lg0, lg1);
    for (int off = 32; off; off >>= 1) mx = fmaxf(mx, __shfl_xor(mx, off));
    float s = (l < 20) ? (__expf(lg0 - mx) + __expf(lg1 - mx)) : 0.f;
    for (int off = 32; off; off >>= 1) s += __shfl_xor(s, off);
    float ls = logf(s);
    if (l < 20) {
        out[(size_t)n * 40 + 2 * l]     = lg0 - mx - ls;
        out[(size_t)n * 40 + 2 * l + 1] = lg1 - mx - ls;
    }
}

extern "C" void kernel_launch(void* const* d_in, const int* in_sizes, int n_in,
                              void* d_out, int out_size, void* d_ws, size_t ws_size,
                              hipStream_t stream) {
    const float* x      = (const float*)d_in[0];
    const int*   ei     = (const int*)d_in[1];
    const float* W1     = (const float*)d_in[2];
    const float* att_s1 = (const float*)d_in[3];
    const float* att_d1 = (const float*)d_in[4];
    const float* b1     = (const float*)d_in[5];
    const float* W2     = (const float*)d_in[6];
    const float* att_s2 = (const float*)d_in[7];
    const float* att_d2 = (const float*)d_in[8];
    const float* b2     = (const float*)d_in[9];

    int N = in_sizes[0] / 256;
    int E = in_sizes[1] / 2;
    int Et = E + N;

    char* ws = (char*)d_ws;
    size_t off = 0;
    auto alloc = [&](size_t bytes) -> void* {
        void* p = ws + off;
        off += (bytes + 255) / 256 * 256;
        return p;
    };
    // xb (bf16 input) and hbh (fp16 agg1 output) share a region: xb dead after gemm1
    unsigned short* xb  = (unsigned short*)alloc((size_t)N * 256 * 2);
    __half*         hbh = (__half*)xb;
    __half* h1h = (__half*)alloc((size_t)N * 256 * 2);
    float* alpha1 = (float*)alloc((size_t)Et * 16);
    float* alpha2 = (float*)alloc((size_t)Et * 4);
    __half* h2h = (__half*)alloc((size_t)N * 40 * 2);
    unsigned short* w1t = (unsigned short*)alloc((size_t)256 * 256 * 2);
    __half* w2t = (__half*)alloc((size_t)48 * 256 * 2);
    float* as1 = (float*)alloc((size_t)N * 4 * 4);
    float* ad1 = (float*)alloc((size_t)N * 4 * 4);
    float* inv1 = (float*)alloc((size_t)N * 4 * 4);
    float* as2 = (float*)alloc((size_t)N * 4);
    float* ad2 = (float*)alloc((size_t)N * 4);
    float* inv2 = (float*)alloc((size_t)N * 4);
    int* deg       = (int*)alloc((size_t)N * 4);
    int* cursor    = (int*)alloc((size_t)N * 4);
    int* row_start = (int*)alloc((size_t)(N + 1) * 4);
    int* csr_src   = (int*)alloc((size_t)Et * 4);
    int* csr_dst   = (int*)alloc((size_t)Et * 4);
    int NB = (N + 255) / 256;
    int* bsums = (int*)alloc((size_t)NB * 4);

    hipMemsetAsync(deg, 0, (size_t)N * 4, stream);
    hipMemsetAsync(cursor, 0, (size_t)N * 4, stream);

    k_deg<<<(Et + 255) / 256, 256, 0, stream>>>(ei, E, N, deg);
    k_scan_block<<<NB, 256, 0, stream>>>(deg, N, row_start, bsums);
    k_scan_sums<<<1, 256, 0, stream>>>(bsums, NB);
    k_scan_add<<<NB, 256, 0, stream>>>(row_start, bsums, N, Et);
    k_scatter<<<(Et + 255) / 256, 256, 0, stream>>>(ei, E, N, row_start, cursor, csr_src, csr_dst);

    k_cvt_x<<<(N * 64 + 255) / 256, 256, 0, stream>>>(x, xb, N * 64);
    k_cvt_w1t<<<256, 256, 0, stream>>>(W1, w1t);
    k_cvt_w2t<<<48, 256, 0, stream>>>(W2, w2t);

    dim3 g1((N + 63) / 64, 4);
    k_gemm1_mfma<<<g1, 256, 0, stream>>>(xb, w1t, att_s1, att_d1, h1h, as1, ad1, N);
    k_edge_e1<<<(Et + 255) / 256, 256, 0, stream>>>(as1, ad1, csr_src, csr_dst, alpha1, Et);
    k_norm1<<<(N + 3) / 4, 256, 0, stream>>>(alpha1, row_start, inv1, N);
    k_agg1<<<(N + 3) / 4, 256, 0, stream>>>(h1h, alpha1, inv1, row_start, csr_src, b1, hbh, N);
    k_gemm2_mfma<<<(N + 63) / 64, 256, 0, stream>>>((const _Float16*)hbh, (const _Float16*)w2t,
                                                    att_s2, att_d2, h2h, as2, ad2, N);
    k_edge_e2<<<(Et + 255) / 256, 256, 0, stream>>>(as2, ad2, csr_src, csr_dst, alpha2, Et);
    k_norm2<<<(N + 3) / 4, 256, 0, stream>>>(alpha2, row_start, inv2, N);
    k_agg2<<<(N + 3) / 4, 256, 0, stream>>>(h2h, alpha2, inv2, row_start, csr_src, b2, (float*)d_out, N);
}

// Round 4
// 259.332 us; speedup vs baseline: 2.0801x; 1.3001x over previous
//
#include <hip/hip_runtime.h>
#include <hip/hip_fp16.h>
#include <math.h>

#define NEG_SLOPE 0.2f

typedef short short8v __attribute__((ext_vector_type(8)));
typedef _Float16 half8v __attribute__((ext_vector_type(8)));
typedef float f32x4 __attribute__((ext_vector_type(4)));

__device__ __forceinline__ unsigned short f2bf(float f) {
    unsigned int u = __builtin_bit_cast(unsigned int, f);
    u += 0x7FFFu + ((u >> 16) & 1u);   // RNE
    return (unsigned short)(u >> 16);
}

__device__ __forceinline__ void fma_h4(float4& acc, float w, uint2 v) {
    __half2 p0 = __builtin_bit_cast(__half2, v.x);
    __half2 p1 = __builtin_bit_cast(__half2, v.y);
    float2 f0 = __half22float2(p0), f1 = __half22float2(p1);
    acc.x += w * f0.x; acc.y += w * f0.y; acc.z += w * f1.x; acc.w += w * f1.y;
}

// ---------------- CSR build ----------------
__global__ void k_deg(const int* __restrict__ ei, int E, int N, int* __restrict__ deg) {
    int i = blockIdx.x * blockDim.x + threadIdx.x;
    int Et = E + N;
    if (i >= Et) return;
    int dst = (i < E) ? ei[E + i] : (i - E);
    atomicAdd(&deg[dst], 1);
}

__global__ void k_scan_block(const int* __restrict__ deg, int N, int* __restrict__ excl, int* __restrict__ bsums) {
    __shared__ int s[256];
    int b = blockIdx.x, t = threadIdx.x;
    int i = b * 256 + t;
    int v = (i < N) ? deg[i] : 0;
    s[t] = v;
    __syncthreads();
    for (int off = 1; off < 256; off <<= 1) {
        int add = (t >= off) ? s[t - off] : 0;
        __syncthreads();
        s[t] += add;
        __syncthreads();
    }
    int incl = s[t];
    if (i < N) excl[i] = incl - v;
    if (t == 255) bsums[b] = incl;
}

__global__ void k_scan_sums(int* __restrict__ bsums, int NB) {
    __shared__ int s[256];
    int t = threadIdx.x;
    int v = (t < NB) ? bsums[t] : 0;
    s[t] = v;
    __syncthreads();
    for (int off = 1; off < 256; off <<= 1) {
        int add = (t >= off) ? s[t - off] : 0;
        __syncthreads();
        s[t] += add;
        __syncthreads();
    }
    if (t < NB) bsums[t] = s[t] - v;  // exclusive
}

__global__ void k_scan_add(int* __restrict__ row_start, const int* __restrict__ bsums, int N, int Et) {
    int i = blockIdx.x * blockDim.x + threadIdx.x;
    if (i < N) row_start[i] += bsums[blockIdx.x];
    if (i == 0) row_start[N] = Et;
}

__global__ void k_scatter(const int* __restrict__ ei, int E, int N, const int* __restrict__ row_start,
                          int* __restrict__ cursor, int* __restrict__ csr_src) {
    int i = blockIdx.x * blockDim.x + threadIdx.x;
    int Et = E + N;
    if (i >= Et) return;
    int src, dst;
    if (i < E) { src = ei[i]; dst = ei[E + i]; }
    else       { src = i - E; dst = i - E; }
    int pos = atomicAdd(&cursor[dst], 1);
    csr_src[row_start[dst] + pos] = src;
}

// ---------------- weight converts ----------------
// W1 [256 in][256 out] -> W1T bf16 [256 out][256 in]
__global__ void k_cvt_w1t(const float* __restrict__ W1, unsigned short* __restrict__ w1t) {
    int n = blockIdx.x, k = threadIdx.x;
    w1t[n * 256 + k] = f2bf(W1[k * 256 + n]);
}

// W2 [256][40] -> W2T fp16 [48 pad][256]
__global__ void k_cvt_w2t(const float* __restrict__ W2, __half* __restrict__ w2t) {
    int c = blockIdx.x, k = threadIdx.x;
    w2t[c * 256 + k] = __float2half((c < 40) ? W2[k * 40 + c] : 0.f);
}

// ---------------- GEMM1 MFMA: A staged from fp32 x, head loop, fused att dots ----------------
#define LDP 264
__global__ __launch_bounds__(256) void k_gemm1_mfma(const float* __restrict__ x,
                                                    const unsigned short* __restrict__ w1t,
                                                    const float* __restrict__ att_s,
                                                    const float* __restrict__ att_d,
                                                    __half* __restrict__ h1h,
                                                    float* __restrict__ as1, float* __restrict__ ad1, int N) {
    __shared__ unsigned short As[64 * LDP];
    __shared__ unsigned short Bs[64 * LDP];
    __shared__ __half Ho[64][72];
    int tid = threadIdx.x;
    int row0 = blockIdx.x * 64;
    // stage A with fused f32->bf16 convert (x read once per block)
#pragma unroll
    for (int it = 0; it < 16; it++) {
        int c = tid + it * 256;        // 4096 chunks of 4 floats
        int r = c >> 6, q = c & 63;
        float4 v = make_float4(0, 0, 0, 0);
        if (row0 + r < N) v = ((const float4*)x)[(size_t)(row0 + r) * 64 + q];
        ushort4 o;
        o.x = f2bf(v.x); o.y = f2bf(v.y); o.z = f2bf(v.z); o.w = f2bf(v.w);
        *(ushort4*)&As[r * LDP + q * 4] = o;
    }
    int w = tid >> 6, l = tid & 63;
    int hi = l >> 4, lo = l & 15;
    for (int head = 0; head < 4; head++) {
        __syncthreads();               // A ready / Bs+Ho from prev head consumed
#pragma unroll
        for (int it = 0; it < 8; it++) {
            int c = tid + it * 256;
            int r = c >> 5, q = c & 31;
            uint4 vb = ((const uint4*)w1t)[(size_t)(head * 64 + r) * 32 + q];
            *(uint4*)&Bs[r * LDP + q * 8] = vb;
        }
        __syncthreads();
        f32x4 acc[4] = {};
#pragma unroll
        for (int kk = 0; kk < 8; kk++) {
            short8v a = *(const short8v*)&As[(16 * w + lo) * LDP + kk * 32 + 8 * hi];
#pragma unroll
            for (int jb = 0; jb < 4; jb++) {
                short8v b = *(const short8v*)&Bs[(16 * jb + lo) * LDP + kk * 32 + 8 * hi];
                acc[jb] = __builtin_amdgcn_mfma_f32_16x16x32_bf16(a, b, acc[jb], 0, 0, 0);
            }
        }
        float asr[4], adr[4];
#pragma unroll
        for (int jb = 0; jb < 4; jb++) {
            int c = head * 64 + lo + 16 * jb;
            asr[jb] = att_s[c];
            adr[jb] = att_d[c];
        }
#pragma unroll
        for (int j = 0; j < 4; j++) {
            int rr = 16 * w + 4 * hi + j;
            float s = 0.f, d = 0.f;
#pragma unroll
            for (int jb = 0; jb < 4; jb++) {
                float v = acc[jb][j];
                s += v * asr[jb];
                d += v * adr[jb];
                Ho[rr][lo + 16 * jb] = __float2half(v);
            }
            s += __shfl_xor(s, 1); s += __shfl_xor(s, 2); s += __shfl_xor(s, 4); s += __shfl_xor(s, 8);
            d += __shfl_xor(d, 1); d += __shfl_xor(d, 2); d += __shfl_xor(d, 4); d += __shfl_xor(d, 8);
            if (lo == 0 && row0 + rr < N) {
                as1[(row0 + rr) * 4 + head] = s;
                ad1[(row0 + rr) * 4 + head] = d;
            }
        }
        __syncthreads();
        // coalesced h1h store from Ho
        int rr = tid >> 2, q = tid & 3;
        int r = row0 + rr;
        if (r < N) {
            uint4 v0 = *(const uint4*)&Ho[rr][q * 16];
            uint4 v1 = *(const uint4*)&Ho[rr][q * 16 + 8];
            *(uint4*)&h1h[(size_t)r * 256 + head * 64 + q * 16] = v0;
            *(uint4*)&h1h[(size_t)r * 256 + head * 64 + q * 16 + 8] = v1;
        }
    }
}

// ---------------- layer1 fused softmax-aggregation ----------------
__global__ __launch_bounds__(256) void k_agg1(const __half* __restrict__ h1h, const float* __restrict__ as1,
                                              const float* __restrict__ ad1, const int* __restrict__ row_start,
                                              const int* __restrict__ csr_src, const float* __restrict__ b1,
                                              __half* __restrict__ hbh, int N) {
    int wv = threadIdx.x >> 6, l = threadIdx.x & 63;
    int n = blockIdx.x * 4 + wv;
    if (n >= N) return;
    int s0 = row_start[n], s1 = row_start[n + 1];
    int head = l >> 4;
    float adv = ad1[n * 4 + head];
    float4 accA = make_float4(0, 0, 0, 0), accB = accA, accC = accA, accD = accA;
    float dA = 0.f, dB = 0.f, dC = 0.f, dD = 0.f;
    int p = s0;
    for (; p + 4 <= s1; p += 4) {
        int sA = csr_src[p], sB = csr_src[p + 1], sC = csr_src[p + 2], sD = csr_src[p + 3];
        float eA = as1[sA * 4 + head] + adv;
        float eB = as1[sB * 4 + head] + adv;
        float eC = as1[sC * 4 + head] + adv;
        float eD = as1[sD * 4 + head] + adv;
        uint2 vA = *(const uint2*)&h1h[(size_t)sA * 256 + 4 * l];
        uint2 vB = *(const uint2*)&h1h[(size_t)sB * 256 + 4 * l];
        uint2 vC = *(const uint2*)&h1h[(size_t)sC * 256 + 4 * l];
        uint2 vD = *(const uint2*)&h1h[(size_t)sD * 256 + 4 * l];
        eA = eA > 0.f ? eA : NEG_SLOPE * eA;
        eB = eB > 0.f ? eB : NEG_SLOPE * eB;
        eC = eC > 0.f ? eC : NEG_SLOPE * eC;
        eD = eD > 0.f ? eD : NEG_SLOPE * eD;
        float wA = __expf(eA), wB = __expf(eB), wC = __expf(eC), wD = __expf(eD);
        dA += wA; dB += wB; dC += wC; dD += wD;
        fma_h4(accA, wA, vA); fma_h4(accB, wB, vB); fma_h4(accC, wC, vC); fma_h4(accD, wD, vD);
    }
    for (; p < s1; p++) {
        int s = csr_src[p];
        float e = as1[s * 4 + head] + adv;
        uint2 v = *(const uint2*)&h1h[(size_t)s * 256 + 4 * l];
        e = e > 0.f ? e : NEG_SLOPE * e;
        float w = __expf(e);
        dA += w;
        fma_h4(accA, w, v);
    }
    float4 acc;
    acc.x = (accA.x + accB.x) + (accC.x + accD.x);
    acc.y = (accA.y + accB.y) + (accC.y + accD.y);
    acc.z = (accA.z + accB.z) + (accC.z + accD.z);
    acc.w = (accA.w + accB.w) + (accC.w + accD.w);
    float inv = 1.f / ((dA + dB) + (dC + dD));
    float4 b = ((const float4*)b1)[l];
    float r0 = acc.x * inv + b.x; r0 = r0 > 0.f ? r0 : 0.f;
    float r1 = acc.y * inv + b.y; r1 = r1 > 0.f ? r1 : 0.f;
    float r2 = acc.z * inv + b.z; r2 = r2 > 0.f ? r2 : 0.f;
    float r3 = acc.w * inv + b.w; r3 = r3 > 0.f ? r3 : 0.f;
    unsigned short u0 = __builtin_bit_cast(unsigned short, __float2half(r0));
    unsigned short u1 = __builtin_bit_cast(unsigned short, __float2half(r1));
    unsigned short u2 = __builtin_bit_cast(unsigned short, __float2half(r2));
    unsigned short u3 = __builtin_bit_cast(unsigned short, __float2half(r3));
    uint2 st;
    st.x = (unsigned)u0 | ((unsigned)u1 << 16);
    st.y = (unsigned)u2 | ((unsigned)u3 << 16);
    *(uint2*)&hbh[(size_t)n * 256 + 4 * l] = st;
}

// ---------------- GEMM2 via f16 MFMA + fused att dots ----------------
__global__ __launch_bounds__(256) void k_gemm2_mfma(const _Float16* __restrict__ hbh,
                                                    const _Float16* __restrict__ w2t,
                                                    const float* __restrict__ att_s2,
                                                    const float* __restrict__ att_d2,
                                                    __half* __restrict__ h2h,
                                                    float* __restrict__ as2, float* __restrict__ ad2, int N) {
    int tid = threadIdx.x, w = tid >> 6, l = tid & 63;
    int hi = l >> 4, lo = l & 15;
    int row0 = blockIdx.x * 64;
    int arow = row0 + 16 * w + lo;
    f32x4 acc[3] = {};
#pragma unroll
    for (int kk = 0; kk < 8; kk++) {
        half8v a = {};
        if (arow < N) a = *(const half8v*)&hbh[(size_t)arow * 256 + kk * 32 + 8 * hi];
#pragma unroll
        for (int jb = 0; jb < 3; jb++) {
            half8v b = *(const half8v*)&w2t[(16 * jb + lo) * 256 + kk * 32 + 8 * hi];
            acc[jb] = __builtin_amdgcn_mfma_f32_16x16x32_f16(a, b, acc[jb], 0, 0, 0);
        }
    }
    float asr[3], adr[3];
#pragma unroll
    for (int jb = 0; jb < 3; jb++) {
        int c = 16 * jb + lo;
        asr[jb] = (c < 40) ? att_s2[c] : 0.f;
        adr[jb] = (c < 40) ? att_d2[c] : 0.f;
    }
#pragma unroll
    for (int j = 0; j < 4; j++) {
        int r = row0 + 16 * w + 4 * hi + j;
        float s = 0.f, d = 0.f;
#pragma unroll
        for (int jb = 0; jb < 3; jb++) {
            float v = acc[jb][j];
            s += v * asr[jb];
            d += v * adr[jb];
            int c = 16 * jb + lo;
            if (c < 40 && r < N) h2h[(size_t)r * 40 + c] = __float2half(v);
        }
        s += __shfl_xor(s, 1); s += __shfl_xor(s, 2); s += __shfl_xor(s, 4); s += __shfl_xor(s, 8);
        d += __shfl_xor(d, 1); d += __shfl_xor(d, 2); d += __shfl_xor(d, 4); d += __shfl_xor(d, 8);
        if (lo == 0 && r < N) { as2[r] = s; ad2[r] = d; }
    }
}

// ---------------- layer2 fused softmax-aggregation + bias + log_softmax ----------------
// 3 groups of 20 lanes; group g handles edges p = pb + g
__global__ __launch_bounds__(256) void k_agg2(const __half* __restrict__ h2h, const float* __restrict__ as2,
                                              const float* __restrict__ ad2, const int* __restrict__ row_start,
                                              const int* __restrict__ csr_src, const float* __restrict__ b2,
                                              float* __restrict__ out, int N) {
    int wv = threadIdx.x >> 6, l = threadIdx.x & 63;
    int n = blockIdx.x * 4 + wv;
    if (n >= N) return;
    int s0 = row_start[n], s1 = row_start[n + 1];
    int grp = l / 20, li = l - grp * 20;     // grp 3 = lanes 60..63 idle
    float ad = ad2[n];
    float2 acc1 = make_float2(0.f, 0.f), acc2 = acc1;
    float den1 = 0.f, den2 = 0.f;
    bool act = grp < 3;
    int pb = s0;
    for (; pb + 6 <= s1; pb += 6) {
        if (act) {
            int pA = pb + grp, pB = pb + 3 + grp;
            int sA = csr_src[pA], sB = csr_src[pB];
            float eA = as2[sA] + ad, eB = as2[sB] + ad;
            unsigned vA = *(const unsigned*)&h2h[(size_t)sA * 40 + 2 * li];
            unsigned vB = *(const unsigned*)&h2h[(size_t)sB * 40 + 2 * li];
            eA = eA > 0.f ? eA : NEG_SLOPE * eA;
            eB = eB > 0.f ? eB : NEG_SLOPE * eB;
            float wA = __expf(eA), wB = __expf(eB);
            den1 += wA; den2 += wB;
            float2 fA = __half22float2(__builtin_bit_cast(__half2, vA));
            float2 fB = __half22float2(__builtin_bit_cast(__half2, vB));
            acc1.x += wA * fA.x; acc1.y += wA * fA.y;
            acc2.x += wB * fB.x; acc2.y += wB * fB.y;
        }
    }
    for (; pb < s1; pb += 3) {
        int p = pb + grp;
        if (act && p < s1) {
            int s = csr_src[p];
            float e = as2[s] + ad;
            e = e > 0.f ? e : NEG_SLOPE * e;
            float w = __expf(e);
            unsigned v = *(const unsigned*)&h2h[(size_t)s * 40 + 2 * li];
            den1 += w;
            float2 f = __half22float2(__builtin_bit_cast(__half2, v));
            acc1.x += w * f.x; acc1.y += w * f.y;
        }
    }
    float den = den1 + den2;
    float ax = acc1.x + acc2.x, ay = acc1.y + acc2.y;
    // cross-group merge
    float den_t = __shfl(den, li) + __shfl(den, 20 + li) + __shfl(den, 40 + li);
    ax += __shfl(ax, l + 20) + __shfl(ax, l + 40);
    ay += __shfl(ay, l + 20) + __shfl(ay, l + 40);
    float inv = 1.f / den_t;
    float lg0 = -1e30f, lg1 = -1e30f;
    if (l < 20) {
        lg0 = ax * inv + b2[2 * l];
        lg1 = ay * inv + b2[2 * l + 1];
    }
    float mx = fmaxf(lg0, lg1);
    for (int off = 32; off; off >>= 1) mx = fmaxf(mx, __shfl_xor(mx, off));
    float s = (l < 20) ? (__expf(lg0 - mx) + __expf(lg1 - mx)) : 0.f;
    for (int off = 32; off; off >>= 1) s += __shfl_xor(s, off);
    float ls = logf(s);
    if (l < 20) {
        out[(size_t)n * 40 + 2 * l]     = lg0 - mx - ls;
        out[(size_t)n * 40 + 2 * l + 1] = lg1 - mx - ls;
    }
}

extern "C" void kernel_launch(void* const* d_in, const int* in_sizes, int n_in,
                              void* d_out, int out_size, void* d_ws, size_t ws_size,
                              hipStream_t stream) {
    const float* x      = (const float*)d_in[0];
    const int*   ei     = (const int*)d_in[1];
    const float* W1     = (const float*)d_in[2];
    const float* att_s1 = (const float*)d_in[3];
    const float* att_d1 = (const float*)d_in[4];
    const float* b1     = (const float*)d_in[5];
    const float* W2     = (const float*)d_in[6];
    const float* att_s2 = (const float*)d_in[7];
    const float* att_d2 = (const float*)d_in[8];
    const float* b2     = (const float*)d_in[9];

    int N = in_sizes[0] / 256;
    int E = in_sizes[1] / 2;
    int Et = E + N;

    char* ws = (char*)d_ws;
    size_t off = 0;
    auto alloc = [&](size_t bytes) -> void* {
        void* p = ws + off;
        off += (bytes + 255) / 256 * 256;
        return p;
    };
    __half* h1h = (__half*)alloc((size_t)N * 256 * 2);
    __half* hbh = (__half*)alloc((size_t)N * 256 * 2);
    __half* h2h = (__half*)alloc((size_t)N * 40 * 2);
    unsigned short* w1t = (unsigned short*)alloc((size_t)256 * 256 * 2);
    __half* w2t = (__half*)alloc((size_t)48 * 256 * 2);
    float* as1 = (float*)alloc((size_t)N * 4 * 4);
    float* ad1 = (float*)alloc((size_t)N * 4 * 4);
    float* as2 = (float*)alloc((size_t)N * 4);
    float* ad2 = (float*)alloc((size_t)N * 4);
    int* deg       = (int*)alloc((size_t)N * 4);
    int* cursor    = (int*)alloc((size_t)N * 4);
    int* row_start = (int*)alloc((size_t)(N + 1) * 4);
    int* csr_src   = (int*)alloc((size_t)Et * 4);
    int NB = (N + 255) / 256;
    int* bsums = (int*)alloc((size_t)NB * 4);

    hipMemsetAsync(deg, 0, (size_t)N * 4, stream);
    hipMemsetAsync(cursor, 0, (size_t)N * 4, stream);

    k_deg<<<(Et + 255) / 256, 256, 0, stream>>>(ei, E, N, deg);
    k_scan_block<<<NB, 256, 0, stream>>>(deg, N, row_start, bsums);
    k_scan_sums<<<1, 256, 0, stream>>>(bsums, NB);
    k_scan_add<<<NB, 256, 0, stream>>>(row_start, bsums, N, Et);
    k_scatter<<<(Et + 255) / 256, 256, 0, stream>>>(ei, E, N, row_start, cursor, csr_src);

    k_cvt_w1t<<<256, 256, 0, stream>>>(W1, w1t);
    k_cvt_w2t<<<48, 256, 0, stream>>>(W2, w2t);

    k_gemm1_mfma<<<(N + 63) / 64, 256, 0, stream>>>(x, w1t, att_s1, att_d1, h1h, as1, ad1, N);
    k_agg1<<<(N + 3) / 4, 256, 0, stream>>>(h1h, as1, ad1, row_start, csr_src, b1, hbh, N);
    k_gemm2_mfma<<<(N + 63) / 64, 256, 0, stream>>>((const _Float16*)hbh, (const _Float16*)w2t,
                                                    att_s2, att_d2, h2h, as2, ad2, N);
    k_agg2<<<(N + 3) / 4, 256, 0, stream>>>(h2h, as2, ad2, row_start, csr_src, b2, (float*)d_out, N);
}

// Round 5
// 220.861 us; speedup vs baseline: 2.4425x; 1.1742x over previous
//
#include <hip/hip_runtime.h>
#include <hip/hip_fp16.h>
#include <math.h>

#define NEG_SLOPE 0.2f

typedef short short8v __attribute__((ext_vector_type(8)));
typedef _Float16 half8v __attribute__((ext_vector_type(8)));
typedef float f32x4 __attribute__((ext_vector_type(4)));

__device__ __forceinline__ unsigned short f2bf(float f) {
    unsigned int u = __builtin_bit_cast(unsigned int, f);
    u += 0x7FFFu + ((u >> 16) & 1u);   // RNE
    return (unsigned short)(u >> 16);
}

__device__ __forceinline__ void fma_h4(float4& acc, float w, uint2 v) {
    __half2 p0 = __builtin_bit_cast(__half2, v.x);
    __half2 p1 = __builtin_bit_cast(__half2, v.y);
    float2 f0 = __half22float2(p0), f1 = __half22float2(p1);
    acc.x += w * f0.x; acc.y += w * f0.y; acc.z += w * f1.x; acc.w += w * f1.y;
}

// ---------------- CSR build ----------------
// deg count; atomic return value = rank of edge within its destination bucket
__global__ void k_deg(const int* __restrict__ ei, int E, int N, int* __restrict__ deg, int* __restrict__ rank) {
    int i = blockIdx.x * blockDim.x + threadIdx.x;
    int Et = E + N;
    if (i >= Et) return;
    int dst = (i < E) ? ei[E + i] : (i - E);
    rank[i] = atomicAdd(&deg[dst], 1);
}

__global__ void k_scan_block(const int* __restrict__ deg, int N, int* __restrict__ excl, int* __restrict__ bsums) {
    __shared__ int s[256];
    int b = blockIdx.x, t = threadIdx.x;
    int i = b * 256 + t;
    int v = (i < N) ? deg[i] : 0;
    s[t] = v;
    __syncthreads();
    for (int off = 1; off < 256; off <<= 1) {
        int add = (t >= off) ? s[t - off] : 0;
        __syncthreads();
        s[t] += add;
        __syncthreads();
    }
    int incl = s[t];
    if (i < N) excl[i] = incl - v;
    if (t == 255) bsums[b] = incl;
}

__global__ void k_scan_sums(int* __restrict__ bsums, int NB) {
    __shared__ int s[256];
    int t = threadIdx.x;
    int v = (t < NB) ? bsums[t] : 0;
    s[t] = v;
    __syncthreads();
    for (int off = 1; off < 256; off <<= 1) {
        int add = (t >= off) ? s[t - off] : 0;
        __syncthreads();
        s[t] += add;
        __syncthreads();
    }
    if (t < NB) bsums[t] = s[t] - v;  // exclusive
}

__global__ void k_scan_add(int* __restrict__ row_start, const int* __restrict__ bsums, int N, int Et) {
    int i = blockIdx.x * blockDim.x + threadIdx.x;
    if (i < N) row_start[i] += bsums[blockIdx.x];
    if (i == 0) row_start[N] = Et;
}

// non-atomic scatter using precomputed rank
__global__ void k_scatter(const int* __restrict__ ei, const int* __restrict__ rank, int E, int N,
                          const int* __restrict__ row_start, int* __restrict__ csr_src) {
    int i = blockIdx.x * blockDim.x + threadIdx.x;
    int Et = E + N;
    if (i >= Et) return;
    int src, dst;
    if (i < E) { src = ei[i]; dst = ei[E + i]; }
    else       { src = i - E; dst = i - E; }
    csr_src[row_start[dst] + rank[i]] = src;
}

// ---------------- weight converts ----------------
// W1 [256 in][256 out] -> W1T bf16 [256 out][256 in]
__global__ void k_cvt_w1t(const float* __restrict__ W1, unsigned short* __restrict__ w1t) {
    int n = blockIdx.x, k = threadIdx.x;
    w1t[n * 256 + k] = f2bf(W1[k * 256 + n]);
}

// W2 [256][40] -> W2T fp16 [48 pad][256]
__global__ void k_cvt_w2t(const float* __restrict__ W2, __half* __restrict__ w2t) {
    int c = blockIdx.x, k = threadIdx.x;
    w2t[c * 256 + k] = __float2half((c < 40) ? W2[k * 40 + c] : 0.f);
}

// ---------------- GEMM1 MFMA: A staged from fp32 x, head loop, fused att dots ----------------
#define LDP 264
__global__ __launch_bounds__(256) void k_gemm1_mfma(const float* __restrict__ x,
                                                    const unsigned short* __restrict__ w1t,
                                                    const float* __restrict__ att_s,
                                                    const float* __restrict__ att_d,
                                                    __half* __restrict__ h1h,
                                                    float* __restrict__ as1, float* __restrict__ ad1, int N) {
    __shared__ unsigned short As[64 * LDP];
    __shared__ unsigned short Bs[64 * LDP];
    int tid = threadIdx.x;
    int row0 = blockIdx.x * 64;
    // stage A with fused f32->bf16 convert (x read once per block)
#pragma unroll
    for (int it = 0; it < 16; it++) {
        int c = tid + it * 256;        // 4096 chunks of 4 floats
        int r = c >> 6, q = c & 63;
        float4 v = make_float4(0, 0, 0, 0);
        if (row0 + r < N) v = ((const float4*)x)[(size_t)(row0 + r) * 64 + q];
        ushort4 o;
        o.x = f2bf(v.x); o.y = f2bf(v.y); o.z = f2bf(v.z); o.w = f2bf(v.w);
        *(ushort4*)&As[r * LDP + q * 4] = o;
    }
    int w = tid >> 6, l = tid & 63;
    int hi = l >> 4, lo = l & 15;
    for (int head = 0; head < 4; head++) {
#pragma unroll
        for (int it = 0; it < 8; it++) {
            int c = tid + it * 256;
            int r = c >> 5, q = c & 31;
            uint4 vb = ((const uint4*)w1t)[(size_t)(head * 64 + r) * 32 + q];
            *(uint4*)&Bs[r * LDP + q * 8] = vb;
        }
        __syncthreads();               // A (first iter) + Bs ready
        f32x4 acc[4] = {};
#pragma unroll
        for (int kk = 0; kk < 8; kk++) {
            short8v a = *(const short8v*)&As[(16 * w + lo) * LDP + kk * 32 + 8 * hi];
#pragma unroll
            for (int jb = 0; jb < 4; jb++) {
                short8v b = *(const short8v*)&Bs[(16 * jb + lo) * LDP + kk * 32 + 8 * hi];
                acc[jb] = __builtin_amdgcn_mfma_f32_16x16x32_bf16(a, b, acc[jb], 0, 0, 0);
            }
        }
        float asr[4], adr[4];
#pragma unroll
        for (int jb = 0; jb < 4; jb++) {
            int c = head * 64 + lo + 16 * jb;
            asr[jb] = att_s[c];
            adr[jb] = att_d[c];
        }
#pragma unroll
        for (int j = 0; j < 4; j++) {
            int rr = 16 * w + 4 * hi + j;
            int r = row0 + rr;
            float s = 0.f, d = 0.f;
#pragma unroll
            for (int jb = 0; jb < 4; jb++) {
                float v = acc[jb][j];
                s += v * asr[jb];
                d += v * adr[jb];
                if (r < N) h1h[(size_t)r * 256 + head * 64 + lo + 16 * jb] = __float2half(v);
            }
            s += __shfl_xor(s, 1); s += __shfl_xor(s, 2); s += __shfl_xor(s, 4); s += __shfl_xor(s, 8);
            d += __shfl_xor(d, 1); d += __shfl_xor(d, 2); d += __shfl_xor(d, 4); d += __shfl_xor(d, 8);
            if (lo == 0 && r < N) {
                as1[r * 4 + head] = s;
                ad1[r * 4 + head] = d;
            }
        }
        if (head < 3) __syncthreads();   // before Bs overwrite
    }
}

// ---------------- layer1 fused softmax-aggregation, 32-bit addressing ----------------
__global__ __launch_bounds__(256) void k_agg1(const __half* __restrict__ h1h, const float* __restrict__ as1,
                                              const float* __restrict__ ad1, const int* __restrict__ row_start,
                                              const int* __restrict__ csr_src, const float* __restrict__ b1,
                                              __half* __restrict__ hbh, int N) {
    int wv = threadIdx.x >> 6, l = threadIdx.x & 63;
    int n = blockIdx.x * 4 + wv;
    if (n >= N) return;
    int s0 = row_start[n], s1 = row_start[n + 1];
    int head = l >> 4;
    unsigned hb4 = (unsigned)head * 4u;     // as1 byte offset within node
    unsigned lb8 = (unsigned)l * 8u;        // h1h byte offset within row
    const char* as1b = (const char*)as1;
    const char* h1b  = (const char*)h1h;
    float adv = ad1[n * 4 + head];
    float4 acc0 = make_float4(0, 0, 0, 0), acc1 = acc0, acc2 = acc0, acc3 = acc0;
    float d0 = 0.f, d1 = 0.f, d2 = 0.f, d3 = 0.f;
    int p = s0;
    for (; p + 8 <= s1; p += 8) {
        int s[8];
#pragma unroll
        for (int i = 0; i < 8; i++) s[i] = csr_src[p + i];
        float e[8]; uint2 v[8];
#pragma unroll
        for (int i = 0; i < 8; i++) {
            e[i] = *(const float*)(as1b + (unsigned)s[i] * 16u + hb4) + adv;
            v[i] = *(const uint2*)(h1b + (unsigned)s[i] * 512u + lb8);
        }
#pragma unroll
        for (int i = 0; i < 8; i++) {
            float ee = e[i] > 0.f ? e[i] : NEG_SLOPE * e[i];
            float wg = __expf(ee);
            if ((i & 3) == 0) { d0 += wg; }
            if ((i & 3) == 1) { d1 += wg; }
            if ((i & 3) == 2) { d2 += wg; }
            if ((i & 3) == 3) { d3 += wg; }
            if ((i & 3) == 0) fma_h4(acc0, wg, v[i]);
            if ((i & 3) == 1) fma_h4(acc1, wg, v[i]);
            if ((i & 3) == 2) fma_h4(acc2, wg, v[i]);
            if ((i & 3) == 3) fma_h4(acc3, wg, v[i]);
        }
    }
    for (; p + 2 <= s1; p += 2) {
        int sA = csr_src[p], sB = csr_src[p + 1];
        float eA = *(const float*)(as1b + (unsigned)sA * 16u + hb4) + adv;
        float eB = *(const float*)(as1b + (unsigned)sB * 16u + hb4) + adv;
        uint2 vA = *(const uint2*)(h1b + (unsigned)sA * 512u + lb8);
        uint2 vB = *(const uint2*)(h1b + (unsigned)sB * 512u + lb8);
        eA = eA > 0.f ? eA : NEG_SLOPE * eA;
        eB = eB > 0.f ? eB : NEG_SLOPE * eB;
        float wA = __expf(eA), wB = __expf(eB);
        d0 += wA; d1 += wB;
        fma_h4(acc0, wA, vA); fma_h4(acc1, wB, vB);
    }
    if (p < s1) {
        int s = csr_src[p];
        float e = *(const float*)(as1b + (unsigned)s * 16u + hb4) + adv;
        uint2 v = *(const uint2*)(h1b + (unsigned)s * 512u + lb8);
        e = e > 0.f ? e : NEG_SLOPE * e;
        float wg = __expf(e);
        d2 += wg;
        fma_h4(acc2, wg, v);
    }
    float4 acc;
    acc.x = (acc0.x + acc1.x) + (acc2.x + acc3.x);
    acc.y = (acc0.y + acc1.y) + (acc2.y + acc3.y);
    acc.z = (acc0.z + acc1.z) + (acc2.z + acc3.z);
    acc.w = (acc0.w + acc1.w) + (acc2.w + acc3.w);
    float inv = 1.f / ((d0 + d1) + (d2 + d3));
    float4 b = ((const float4*)b1)[l];
    float r0 = acc.x * inv + b.x; r0 = r0 > 0.f ? r0 : 0.f;
    float r1 = acc.y * inv + b.y; r1 = r1 > 0.f ? r1 : 0.f;
    float r2 = acc.z * inv + b.z; r2 = r2 > 0.f ? r2 : 0.f;
    float r3 = acc.w * inv + b.w; r3 = r3 > 0.f ? r3 : 0.f;
    unsigned short u0 = __builtin_bit_cast(unsigned short, __float2half(r0));
    unsigned short u1 = __builtin_bit_cast(unsigned short, __float2half(r1));
    unsigned short u2 = __builtin_bit_cast(unsigned short, __float2half(r2));
    unsigned short u3 = __builtin_bit_cast(unsigned short, __float2half(r3));
    uint2 st;
    st.x = (unsigned)u0 | ((unsigned)u1 << 16);
    st.y = (unsigned)u2 | ((unsigned)u3 << 16);
    *(uint2*)((char*)hbh + (unsigned)n * 512u + lb8) = st;
}

// ---------------- GEMM2 via f16 MFMA + fused att dots ----------------
__global__ __launch_bounds__(256) void k_gemm2_mfma(const _Float16* __restrict__ hbh,
                                                    const _Float16* __restrict__ w2t,
                                                    const float* __restrict__ att_s2,
                                                    const float* __restrict__ att_d2,
                                                    __half* __restrict__ h2h,
                                                    float* __restrict__ as2, float* __restrict__ ad2, int N) {
    int tid = threadIdx.x, w = tid >> 6, l = tid & 63;
    int hi = l >> 4, lo = l & 15;
    int row0 = blockIdx.x * 64;
    int arow = row0 + 16 * w + lo;
    const char* hb = (const char*)hbh;
    f32x4 acc[3] = {};
#pragma unroll
    for (int kk = 0; kk < 8; kk++) {
        half8v a = {};
        if (arow < N) a = *(const half8v*)(hb + (unsigned)arow * 512u + (unsigned)(kk * 64 + 16 * hi));
#pragma unroll
        for (int jb = 0; jb < 3; jb++) {
            half8v b = *(const half8v*)&w2t[(16 * jb + lo) * 256 + kk * 32 + 8 * hi];
            acc[jb] = __builtin_amdgcn_mfma_f32_16x16x32_f16(a, b, acc[jb], 0, 0, 0);
        }
    }
    float asr[3], adr[3];
#pragma unroll
    for (int jb = 0; jb < 3; jb++) {
        int c = 16 * jb + lo;
        asr[jb] = (c < 40) ? att_s2[c] : 0.f;
        adr[jb] = (c < 40) ? att_d2[c] : 0.f;
    }
#pragma unroll
    for (int j = 0; j < 4; j++) {
        int r = row0 + 16 * w + 4 * hi + j;
        float s = 0.f, d = 0.f;
#pragma unroll
        for (int jb = 0; jb < 3; jb++) {
            float v = acc[jb][j];
            s += v * asr[jb];
            d += v * adr[jb];
            int c = 16 * jb + lo;
            if (c < 40 && r < N) h2h[(size_t)r * 40 + c] = __float2half(v);
        }
        s += __shfl_xor(s, 1); s += __shfl_xor(s, 2); s += __shfl_xor(s, 4); s += __shfl_xor(s, 8);
        d += __shfl_xor(d, 1); d += __shfl_xor(d, 2); d += __shfl_xor(d, 4); d += __shfl_xor(d, 8);
        if (lo == 0 && r < N) { as2[r] = s; ad2[r] = d; }
    }
}

// ---------------- layer2 fused softmax-aggregation + bias + log_softmax ----------------
// 3 groups of 20 lanes; group g handles edges p = pb + g
__global__ __launch_bounds__(256) void k_agg2(const __half* __restrict__ h2h, const float* __restrict__ as2,
                                              const float* __restrict__ ad2, const int* __restrict__ row_start,
                                              const int* __restrict__ csr_src, const float* __restrict__ b2,
                                              float* __restrict__ out, int N) {
    int wv = threadIdx.x >> 6, l = threadIdx.x & 63;
    int n = blockIdx.x * 4 + wv;
    if (n >= N) return;
    int s0 = row_start[n], s1 = row_start[n + 1];
    int grp = l / 20, li = l - grp * 20;     // grp 3 = lanes 60..63 idle
    unsigned li4 = (unsigned)li * 4u;
    const char* h2b = (const char*)h2h;
    const char* as2b = (const char*)as2;
    float ad = ad2[n];
    float2 acc1 = make_float2(0.f, 0.f), acc2 = acc1;
    float den1 = 0.f, den2 = 0.f;
    bool act = grp < 3;
    int pb = s0;
    for (; pb + 6 <= s1; pb += 6) {
        if (act) {
            int pA = pb + grp, pB = pb + 3 + grp;
            int sA = csr_src[pA], sB = csr_src[pB];
            float eA = *(const float*)(as2b + (unsigned)sA * 4u) + ad;
            float eB = *(const float*)(as2b + (unsigned)sB * 4u) + ad;
            unsigned vA = *(const unsigned*)(h2b + (unsigned)sA * 80u + li4);
            unsigned vB = *(const unsigned*)(h2b + (unsigned)sB * 80u + li4);
            eA = eA > 0.f ? eA : NEG_SLOPE * eA;
            eB = eB > 0.f ? eB : NEG_SLOPE * eB;
            float wA = __expf(eA), wB = __expf(eB);
            den1 += wA; den2 += wB;
            float2 fA = __half22float2(__builtin_bit_cast(__half2, vA));
            float2 fB = __half22float2(__builtin_bit_cast(__half2, vB));
            acc1.x += wA * fA.x; acc1.y += wA * fA.y;
            acc2.x += wB * fB.x; acc2.y += wB * fB.y;
        }
    }
    for (; pb < s1; pb += 3) {
        int p = pb + grp;
        if (act && p < s1) {
            int s = csr_src[p];
            float e = *(const float*)(as2b + (unsigned)s * 4u) + ad;
            e = e > 0.f ? e : NEG_SLOPE * e;
            float w = __expf(e);
            unsigned v = *(const unsigned*)(h2b + (unsigned)s * 80u + li4);
            den1 += w;
            float2 f = __half22float2(__builtin_bit_cast(__half2, v));
            acc1.x += w * f.x; acc1.y += w * f.y;
        }
    }
    float den = den1 + den2;
    float ax = acc1.x + acc2.x, ay = acc1.y + acc2.y;
    // cross-group merge
    float den_t = __shfl(den, li) + __shfl(den, 20 + li) + __shfl(den, 40 + li);
    ax += __shfl(ax, l + 20) + __shfl(ax, l + 40);
    ay += __shfl(ay, l + 20) + __shfl(ay, l + 40);
    float inv = 1.f / den_t;
    float lg0 = -1e30f, lg1 = -1e30f;
    if (l < 20) {
        lg0 = ax * inv + b2[2 * l];
        lg1 = ay * inv + b2[2 * l + 1];
    }
    float mx = fmaxf(lg0, lg1);
    for (int off = 32; off; off >>= 1) mx = fmaxf(mx, __shfl_xor(mx, off));
    float s = (l < 20) ? (__expf(lg0 - mx) + __expf(lg1 - mx)) : 0.f;
    for (int off = 32; off; off >>= 1) s += __shfl_xor(s, off);
    float ls = logf(s);
    if (l < 20) {
        out[(size_t)n * 40 + 2 * l]     = lg0 - mx - ls;
        out[(size_t)n * 40 + 2 * l + 1] = lg1 - mx - ls;
    }
}

extern "C" void kernel_launch(void* const* d_in, const int* in_sizes, int n_in,
                              void* d_out, int out_size, void* d_ws, size_t ws_size,
                              hipStream_t stream) {
    const float* x      = (const float*)d_in[0];
    const int*   ei     = (const int*)d_in[1];
    const float* W1     = (const float*)d_in[2];
    const float* att_s1 = (const float*)d_in[3];
    const float* att_d1 = (const float*)d_in[4];
    const float* b1     = (const float*)d_in[5];
    const float* W2     = (const float*)d_in[6];
    const float* att_s2 = (const float*)d_in[7];
    const float* att_d2 = (const float*)d_in[8];
    const float* b2     = (const float*)d_in[9];

    int N = in_sizes[0] / 256;
    int E = in_sizes[1] / 2;
    int Et = E + N;

    char* ws = (char*)d_ws;
    size_t off = 0;
    auto alloc = [&](size_t bytes) -> void* {
        void* p = ws + off;
        off += (bytes + 255) / 256 * 256;
        return p;
    };
    __half* h1h = (__half*)alloc((size_t)N * 256 * 2);
    __half* hbh = (__half*)alloc((size_t)N * 256 * 2);
    __half* h2h = (__half*)alloc((size_t)N * 40 * 2);
    unsigned short* w1t = (unsigned short*)alloc((size_t)256 * 256 * 2);
    __half* w2t = (__half*)alloc((size_t)48 * 256 * 2);
    float* as1 = (float*)alloc((size_t)N * 4 * 4);
    float* ad1 = (float*)alloc((size_t)N * 4 * 4);
    float* as2 = (float*)alloc((size_t)N * 4);
    float* ad2 = (float*)alloc((size_t)N * 4);
    int* deg       = (int*)alloc((size_t)N * 4);
    int* rank      = (int*)alloc((size_t)Et * 4);
    int* row_start = (int*)alloc((size_t)(N + 1) * 4);
    int* csr_src   = (int*)alloc((size_t)Et * 4);
    int NB = (N + 255) / 256;
    int* bsums = (int*)alloc((size_t)NB * 4);

    hipMemsetAsync(deg, 0, (size_t)N * 4, stream);

    k_deg<<<(Et + 255) / 256, 256, 0, stream>>>(ei, E, N, deg, rank);
    k_scan_block<<<NB, 256, 0, stream>>>(deg, N, row_start, bsums);
    k_scan_sums<<<1, 256, 0, stream>>>(bsums, NB);
    k_scan_add<<<NB, 256, 0, stream>>>(row_start, bsums, N, Et);
    k_scatter<<<(Et + 255) / 256, 256, 0, stream>>>(ei, rank, E, N, row_start, csr_src);

    k_cvt_w1t<<<256, 256, 0, stream>>>(W1, w1t);
    k_cvt_w2t<<<48, 256, 0, stream>>>(W2, w2t);

    k_gemm1_mfma<<<(N + 63) / 64, 256, 0, stream>>>(x, w1t, att_s1, att_d1, h1h, as1, ad1, N);
    k_agg1<<<(N + 3) / 4, 256, 0, stream>>>(h1h, as1, ad1, row_start, csr_src, b1, hbh, N);
    k_gemm2_mfma<<<(N + 63) / 64, 256, 0, stream>>>((const _Float16*)hbh, (const _Float16*)w2t,
                                                    att_s2, att_d2, h2h, as2, ad2, N);
    k_agg2<<<(N + 3) / 4, 256, 0, stream>>>(h2h, as2, ad2, row_start, csr_src, b2, (float*)d_out, N);
}

// Round 6
// 217.090 us; speedup vs baseline: 2.4849x; 1.0174x over previous
//
#include <hip/hip_runtime.h>
#include <hip/hip_fp16.h>
#include <math.h>

#define NEG_SLOPE 0.2f

typedef short short8v __attribute__((ext_vector_type(8)));
typedef _Float16 half8v __attribute__((ext_vector_type(8)));
typedef float f32x4 __attribute__((ext_vector_type(4)));

__device__ __forceinline__ unsigned short f2bf(float f) {
    unsigned int u = __builtin_bit_cast(unsigned int, f);
    u += 0x7FFFu + ((u >> 16) & 1u);   // RNE
    return (unsigned short)(u >> 16);
}

__device__ __forceinline__ void fma_h4(float4& acc, float w, uint2 v) {
    __half2 p0 = __builtin_bit_cast(__half2, v.x);
    __half2 p1 = __builtin_bit_cast(__half2, v.y);
    float2 f0 = __half22float2(p0), f1 = __half22float2(p1);
    acc.x += w * f0.x; acc.y += w * f0.y; acc.z += w * f1.x; acc.w += w * f1.y;
}

// ---------------- CSR build ----------------
__global__ void k_deg(const int* __restrict__ ei, int E, int N, int* __restrict__ deg, int* __restrict__ rank) {
    int i = blockIdx.x * blockDim.x + threadIdx.x;
    int Et = E + N;
    if (i >= Et) return;
    int dst = (i < E) ? ei[E + i] : (i - E);
    rank[i] = atomicAdd(&deg[dst], 1);
}

__global__ void k_scan_block(const int* __restrict__ deg, int N, int* __restrict__ excl, int* __restrict__ bsums) {
    __shared__ int s[256];
    int b = blockIdx.x, t = threadIdx.x;
    int i = b * 256 + t;
    int v = (i < N) ? deg[i] : 0;
    s[t] = v;
    __syncthreads();
    for (int off = 1; off < 256; off <<= 1) {
        int add = (t >= off) ? s[t - off] : 0;
        __syncthreads();
        s[t] += add;
        __syncthreads();
    }
    int incl = s[t];
    if (i < N) excl[i] = incl - v;
    if (t == 255) bsums[b] = incl;
}

__global__ void k_scan_sums(int* __restrict__ bsums, int NB) {
    __shared__ int s[256];
    int t = threadIdx.x;
    int v = (t < NB) ? bsums[t] : 0;
    s[t] = v;
    __syncthreads();
    for (int off = 1; off < 256; off <<= 1) {
        int add = (t >= off) ? s[t - off] : 0;
        __syncthreads();
        s[t] += add;
        __syncthreads();
    }
    if (t < NB) bsums[t] = s[t] - v;  // exclusive
}

__global__ void k_scan_add(int* __restrict__ row_start, const int* __restrict__ bsums, int N, int Et) {
    int i = blockIdx.x * blockDim.x + threadIdx.x;
    if (i < N) row_start[i] += bsums[blockIdx.x];
    if (i == 0) row_start[N] = Et;
}

__global__ void k_scatter(const int* __restrict__ ei, const int* __restrict__ rank, int E, int N,
                          const int* __restrict__ row_start, int* __restrict__ csr_src) {
    int i = blockIdx.x * blockDim.x + threadIdx.x;
    int Et = E + N;
    if (i >= Et) return;
    int src, dst;
    if (i < E) { src = ei[i]; dst = ei[E + i]; }
    else       { src = i - E; dst = i - E; }
    csr_src[row_start[dst] + rank[i]] = src;
}

// ---------------- weight converts (merged) ----------------
// blocks 0..255: W1T row; blocks 256..303: W2T row
__global__ void k_cvt_w(const float* __restrict__ W1, const float* __restrict__ W2,
                        unsigned short* __restrict__ w1t, __half* __restrict__ w2t) {
    int b = blockIdx.x, k = threadIdx.x;
    if (b < 256) {
        w1t[b * 256 + k] = f2bf(W1[k * 256 + b]);
    } else {
        int c = b - 256;
        w2t[c * 256 + k] = __float2half((c < 40) ? W2[k * 40 + c] : 0.f);
    }
}

// ---------------- GEMM1 MFMA: A staged from fp32 x, head loop, fused att dots ----------------
#define LDP 264
__global__ __launch_bounds__(256) void k_gemm1_mfma(const float* __restrict__ x,
                                                    const unsigned short* __restrict__ w1t,
                                                    const float* __restrict__ att_s,
                                                    const float* __restrict__ att_d,
                                                    __half* __restrict__ h1h,
                                                    float* __restrict__ as1, float* __restrict__ ad1, int N) {
    __shared__ unsigned short As[64 * LDP];
    __shared__ unsigned short Bs[64 * LDP];
    int tid = threadIdx.x;
    int row0 = blockIdx.x * 64;
    // stage A with fused f32->bf16 convert (x read once per block)
#pragma unroll
    for (int it = 0; it < 16; it++) {
        int c = tid + it * 256;        // 4096 chunks of 4 floats
        int r = c >> 6, q = c & 63;
        float4 v = make_float4(0, 0, 0, 0);
        if (row0 + r < N) v = ((const float4*)x)[(size_t)(row0 + r) * 64 + q];
        ushort4 o;
        o.x = f2bf(v.x); o.y = f2bf(v.y); o.z = f2bf(v.z); o.w = f2bf(v.w);
        *(ushort4*)&As[r * LDP + q * 4] = o;
    }
    int w = tid >> 6, l = tid & 63;
    int hi = l >> 4, lo = l & 15;
    for (int head = 0; head < 4; head++) {
#pragma unroll
        for (int it = 0; it < 8; it++) {
            int c = tid + it * 256;
            int r = c >> 5, q = c & 31;
            uint4 vb = ((const uint4*)w1t)[(size_t)(head * 64 + r) * 32 + q];
            *(uint4*)&Bs[r * LDP + q * 8] = vb;
        }
        __syncthreads();               // A (first iter) + Bs ready
        f32x4 acc[4] = {};
#pragma unroll
        for (int kk = 0; kk < 8; kk++) {
            short8v a = *(const short8v*)&As[(16 * w + lo) * LDP + kk * 32 + 8 * hi];
#pragma unroll
            for (int jb = 0; jb < 4; jb++) {
                short8v b = *(const short8v*)&Bs[(16 * jb + lo) * LDP + kk * 32 + 8 * hi];
                acc[jb] = __builtin_amdgcn_mfma_f32_16x16x32_bf16(a, b, acc[jb], 0, 0, 0);
            }
        }
        float asr[4], adr[4];
#pragma unroll
        for (int jb = 0; jb < 4; jb++) {
            int c = head * 64 + lo + 16 * jb;
            asr[jb] = att_s[c];
            adr[jb] = att_d[c];
        }
#pragma unroll
        for (int j = 0; j < 4; j++) {
            int rr = 16 * w + 4 * hi + j;
            int r = row0 + rr;
            float s = 0.f, d = 0.f;
#pragma unroll
            for (int jb = 0; jb < 4; jb++) {
                float v = acc[jb][j];
                s += v * asr[jb];
                d += v * adr[jb];
                if (r < N) h1h[(size_t)r * 256 + head * 64 + lo + 16 * jb] = __float2half(v);
            }
            s += __shfl_xor(s, 1); s += __shfl_xor(s, 2); s += __shfl_xor(s, 4); s += __shfl_xor(s, 8);
            d += __shfl_xor(d, 1); d += __shfl_xor(d, 2); d += __shfl_xor(d, 4); d += __shfl_xor(d, 8);
            if (lo == 0 && r < N) {
                as1[r * 4 + head] = s;
                ad1[r * 4 + head] = d;
            }
        }
        if (head < 3) __syncthreads();   // before Bs overwrite
    }
}

// ---------------- layer1 fused softmax-aggregation: 2-phase per 64-edge chunk ----------------
__global__ __launch_bounds__(256) void k_agg1(const __half* __restrict__ h1h, const float* __restrict__ as1,
                                              const float* __restrict__ ad1, const int* __restrict__ row_start,
                                              const int* __restrict__ csr_src, const float* __restrict__ b1,
                                              __half* __restrict__ hbh, int N) {
    __shared__ int    s_src[4][64];
    __shared__ float4 s_w[4][64];
    int wv = threadIdx.x >> 6, l = threadIdx.x & 63;
    int n = blockIdx.x * 4 + wv;
    if (n >= N) return;
    int s0 = row_start[n], s1 = row_start[n + 1];
    int head = l >> 4;
    unsigned lb8 = (unsigned)l * 8u;
    const char* h1b = (const char*)h1h;
    float4 adv = ((const float4*)ad1)[n];
    float4 acc0 = make_float4(0, 0, 0, 0), acc1 = acc0, acc2 = acc0, acc3 = acc0;
    float den = 0.f;
    for (int c0 = s0; c0 < s1; c0 += 64) {
        int cl = min(64, s1 - c0);
        // phase 1: lane i owns edge i — coalesced id load, 1 gather, 4 exps/edge total
        if (l < cl) {
            int si = csr_src[c0 + l];
            s_src[wv][l] = si;
            float4 a = ((const float4*)as1)[si];
            float4 e;
            e.x = a.x + adv.x; e.x = e.x > 0.f ? e.x : NEG_SLOPE * e.x; e.x = __expf(e.x);
            e.y = a.y + adv.y; e.y = e.y > 0.f ? e.y : NEG_SLOPE * e.y; e.y = __expf(e.y);
            e.z = a.z + adv.z; e.z = e.z > 0.f ? e.z : NEG_SLOPE * e.z; e.z = __expf(e.z);
            e.w = a.w + adv.w; e.w = e.w > 0.f ? e.w : NEG_SLOPE * e.w; e.w = __expf(e.w);
            s_w[wv][l] = e;
        }
        // phase 2: weighted gather; src/w via LDS broadcast reads
        int p = 0;
        for (; p + 4 <= cl; p += 4) {
            int sA = s_src[wv][p],     sB = s_src[wv][p + 1];
            int sC = s_src[wv][p + 2], sD = s_src[wv][p + 3];
            float wA = ((const float*)&s_w[wv][p    ])[head];
            float wB = ((const float*)&s_w[wv][p + 1])[head];
            float wC = ((const float*)&s_w[wv][p + 2])[head];
            float wD = ((const float*)&s_w[wv][p + 3])[head];
            uint2 vA = *(const uint2*)(h1b + (unsigned)sA * 512u + lb8);
            uint2 vB = *(const uint2*)(h1b + (unsigned)sB * 512u + lb8);
            uint2 vC = *(const uint2*)(h1b + (unsigned)sC * 512u + lb8);
            uint2 vD = *(const uint2*)(h1b + (unsigned)sD * 512u + lb8);
            den += (wA + wB) + (wC + wD);
            fma_h4(acc0, wA, vA); fma_h4(acc1, wB, vB);
            fma_h4(acc2, wC, vC); fma_h4(acc3, wD, vD);
        }
        for (; p < cl; p++) {
            int s = s_src[wv][p];
            float wg = ((const float*)&s_w[wv][p])[head];
            uint2 v = *(const uint2*)(h1b + (unsigned)s * 512u + lb8);
            den += wg;
            fma_h4(acc0, wg, v);
        }
    }
    float4 acc;
    acc.x = (acc0.x + acc1.x) + (acc2.x + acc3.x);
    acc.y = (acc0.y + acc1.y) + (acc2.y + acc3.y);
    acc.z = (acc0.z + acc1.z) + (acc2.z + acc3.z);
    acc.w = (acc0.w + acc1.w) + (acc2.w + acc3.w);
    float inv = 1.f / den;
    float4 b = ((const float4*)b1)[l];
    float r0 = acc.x * inv + b.x; r0 = r0 > 0.f ? r0 : 0.f;
    float r1 = acc.y * inv + b.y; r1 = r1 > 0.f ? r1 : 0.f;
    float r2 = acc.z * inv + b.z; r2 = r2 > 0.f ? r2 : 0.f;
    float r3 = acc.w * inv + b.w; r3 = r3 > 0.f ? r3 : 0.f;
    unsigned short u0 = __builtin_bit_cast(unsigned short, __float2half(r0));
    unsigned short u1 = __builtin_bit_cast(unsigned short, __float2half(r1));
    unsigned short u2 = __builtin_bit_cast(unsigned short, __float2half(r2));
    unsigned short u3 = __builtin_bit_cast(unsigned short, __float2half(r3));
    uint2 st;
    st.x = (unsigned)u0 | ((unsigned)u1 << 16);
    st.y = (unsigned)u2 | ((unsigned)u3 << 16);
    *(uint2*)((char*)hbh + (unsigned)n * 512u + lb8) = st;
}

// ---------------- GEMM2 via f16 MFMA + fused att dots ----------------
__global__ __launch_bounds__(256) void k_gemm2_mfma(const _Float16* __restrict__ hbh,
                                                    const _Float16* __restrict__ w2t,
                                                    const float* __restrict__ att_s2,
                                                    const float* __restrict__ att_d2,
                                                    __half* __restrict__ h2h,
                                                    float* __restrict__ as2, float* __restrict__ ad2, int N) {
    int tid = threadIdx.x, w = tid >> 6, l = tid & 63;
    int hi = l >> 4, lo = l & 15;
    int row0 = blockIdx.x * 64;
    int arow = row0 + 16 * w + lo;
    const char* hb = (const char*)hbh;
    f32x4 acc[3] = {};
#pragma unroll
    for (int kk = 0; kk < 8; kk++) {
        half8v a = {};
        if (arow < N) a = *(const half8v*)(hb + (unsigned)arow * 512u + (unsigned)(kk * 64 + 16 * hi));
#pragma unroll
        for (int jb = 0; jb < 3; jb++) {
            half8v b = *(const half8v*)&w2t[(16 * jb + lo) * 256 + kk * 32 + 8 * hi];
            acc[jb] = __builtin_amdgcn_mfma_f32_16x16x32_f16(a, b, acc[jb], 0, 0, 0);
        }
    }
    float asr[3], adr[3];
#pragma unroll
    for (int jb = 0; jb < 3; jb++) {
        int c = 16 * jb + lo;
        asr[jb] = (c < 40) ? att_s2[c] : 0.f;
        adr[jb] = (c < 40) ? att_d2[c] : 0.f;
    }
#pragma unroll
    for (int j = 0; j < 4; j++) {
        int r = row0 + 16 * w + 4 * hi + j;
        float s = 0.f, d = 0.f;
#pragma unroll
        for (int jb = 0; jb < 3; jb++) {
            float v = acc[jb][j];
            s += v * asr[jb];
            d += v * adr[jb];
            int c = 16 * jb + lo;
            if (c < 40 && r < N) h2h[(size_t)r * 40 + c] = __float2half(v);
        }
        s += __shfl_xor(s, 1); s += __shfl_xor(s, 2); s += __shfl_xor(s, 4); s += __shfl_xor(s, 8);
        d += __shfl_xor(d, 1); d += __shfl_xor(d, 2); d += __shfl_xor(d, 4); d += __shfl_xor(d, 8);
        if (lo == 0 && r < N) { as2[r] = s; ad2[r] = d; }
    }
}

// ---------------- layer2 fused softmax-aggregation + bias + log_softmax: 2-phase ----------------
__global__ __launch_bounds__(256) void k_agg2(const __half* __restrict__ h2h, const float* __restrict__ as2,
                                              const float* __restrict__ ad2, const int* __restrict__ row_start,
                                              const int* __restrict__ csr_src, const float* __restrict__ b2,
                                              float* __restrict__ out, int N) {
    __shared__ int   s_src[4][64];
    __shared__ float s_w[4][64];
    int wv = threadIdx.x >> 6, l = threadIdx.x & 63;
    int n = blockIdx.x * 4 + wv;
    if (n >= N) return;
    int s0 = row_start[n], s1 = row_start[n + 1];
    int grp = l / 20, li = l - grp * 20;     // grp 3 = lanes 60..63 idle in phase 2
    unsigned li4 = (unsigned)li * 4u;
    const char* h2b = (const char*)h2h;
    float ad = ad2[n];
    float2 acc = make_float2(0.f, 0.f);
    float den = 0.f;
    bool act = grp < 3;
    for (int c0 = s0; c0 < s1; c0 += 64) {
        int cl = min(64, s1 - c0);
        // phase 1: lane i owns edge i — 1 exp/edge total
        if (l < cl) {
            int si = csr_src[c0 + l];
            s_src[wv][l] = si;
            float e = as2[si] + ad;
            e = e > 0.f ? e : NEG_SLOPE * e;
            s_w[wv][l] = __expf(e);
        }
        // phase 2: 3 groups of 20 lanes; group g takes every 3rd edge
        if (act) {
            for (int p = grp; p < cl; p += 3) {
                int si = s_src[wv][p];
                float w = s_w[wv][p];
                unsigned v = *(const unsigned*)(h2b + (unsigned)si * 80u + li4);
                den += w;
                float2 f = __half22float2(__builtin_bit_cast(__half2, v));
                acc.x += w * f.x; acc.y += w * f.y;
            }
        }
    }
    // cross-group merge
    float den_t = __shfl(den, li) + __shfl(den, 20 + li) + __shfl(den, 40 + li);
    float ax = acc.x + __shfl(acc.x, l + 20) + __shfl(acc.x, l + 40);
    float ay = acc.y + __shfl(acc.y, l + 20) + __shfl(acc.y, l + 40);
    float inv = 1.f / den_t;
    float lg0 = -1e30f, lg1 = -1e30f;
    if (l < 20) {
        lg0 = ax * inv + b2[2 * l];
        lg1 = ay * inv + b2[2 * l + 1];
    }
    float mx = fmaxf(lg0, lg1);
    for (int off = 32; off; off >>= 1) mx = fmaxf(mx, __shfl_xor(mx, off));
    float s = (l < 20) ? (__expf(lg0 - mx) + __expf(lg1 - mx)) : 0.f;
    for (int off = 32; off; off >>= 1) s += __shfl_xor(s, off);
    float ls = logf(s);
    if (l < 20) {
        out[(size_t)n * 40 + 2 * l]     = lg0 - mx - ls;
        out[(size_t)n * 40 + 2 * l + 1] = lg1 - mx - ls;
    }
}

extern "C" void kernel_launch(void* const* d_in, const int* in_sizes, int n_in,
                              void* d_out, int out_size, void* d_ws, size_t ws_size,
                              hipStream_t stream) {
    const float* x      = (const float*)d_in[0];
    const int*   ei     = (const int*)d_in[1];
    const float* W1     = (const float*)d_in[2];
    const float* att_s1 = (const float*)d_in[3];
    const float* att_d1 = (const float*)d_in[4];
    const float* b1     = (const float*)d_in[5];
    const float* W2     = (const float*)d_in[6];
    const float* att_s2 = (const float*)d_in[7];
    const float* att_d2 = (const float*)d_in[8];
    const float* b2     = (const float*)d_in[9];

    int N = in_sizes[0] / 256;
    int E = in_sizes[1] / 2;
    int Et = E + N;

    char* ws = (char*)d_ws;
    size_t off = 0;
    auto alloc = [&](size_t bytes) -> void* {
        void* p = ws + off;
        off += (bytes + 255) / 256 * 256;
        return p;
    };
    __half* h1h = (__half*)alloc((size_t)N * 256 * 2);
    __half* hbh = (__half*)alloc((size_t)N * 256 * 2);
    __half* h2h = (__half*)alloc((size_t)N * 40 * 2);
    unsigned short* w1t = (unsigned short*)alloc((size_t)256 * 256 * 2);
    __half* w2t = (__half*)alloc((size_t)48 * 256 * 2);
    float* as1 = (float*)alloc((size_t)N * 4 * 4);
    float* ad1 = (float*)alloc((size_t)N * 4 * 4);
    float* as2 = (float*)alloc((size_t)N * 4);
    float* ad2 = (float*)alloc((size_t)N * 4);
    int* deg       = (int*)alloc((size_t)N * 4);
    int* rank      = (int*)alloc((size_t)Et * 4);
    int* row_start = (int*)alloc((size_t)(N + 1) * 4);
    int* csr_src   = (int*)alloc((size_t)Et * 4);
    int NB = (N + 255) / 256;
    int* bsums = (int*)alloc((size_t)NB * 4);

    hipMemsetAsync(deg, 0, (size_t)N * 4, stream);

    k_deg<<<(Et + 255) / 256, 256, 0, stream>>>(ei, E, N, deg, rank);
    k_scan_block<<<NB, 256, 0, stream>>>(deg, N, row_start, bsums);
    k_scan_sums<<<1, 256, 0, stream>>>(bsums, NB);
    k_scan_add<<<NB, 256, 0, stream>>>(row_start, bsums, N, Et);
    k_scatter<<<(Et + 255) / 256, 256, 0, stream>>>(ei, rank, E, N, row_start, csr_src);

    k_cvt_w<<<304, 256, 0, stream>>>(W1, W2, w1t, w2t);

    k_gemm1_mfma<<<(N + 63) / 64, 256, 0, stream>>>(x, w1t, att_s1, att_d1, h1h, as1, ad1, N);
    k_agg1<<<(N + 3) / 4, 256, 0, stream>>>(h1h, as1, ad1, row_start, csr_src, b1, hbh, N);
    k_gemm2_mfma<<<(N + 63) / 64, 256, 0, stream>>>((const _Float16*)hbh, (const _Float16*)w2t,
                                                    att_s2, att_d2, h2h, as2, ad2, N);
    k_agg2<<<(N + 3) / 4, 256, 0, stream>>>(h2h, as2, ad2, row_start, csr_src, b2, (float*)d_out, N);
}